// Round 3
// baseline (609.648 us; speedup 1.0000x reference)
//
#include <hip/hip_runtime.h>
#include <hip/hip_bf16.h>
#include <math.h>

constexpr int kB = 16;
constexpr int kS = 256;
constexpr int kT = 1024;
constexpr int kM = 5151;
constexpr int kH = 256;
constexpr int kChunks = 21;              // ceil(M/256)
constexpr int kWavesPerB = kChunks * 4;  // 84
constexpr float kSig = 1442.6950408889634f; // 1000 * log2(e)

constexpr int OFF_BOUT = 0;
constexpr int OFF_DENS = kB * kT;                 // 16384
constexpr int OFF_M    = OFF_DENS + kB * kM;      // 98800
constexpr int OFF_IS   = OFF_M + kB * kT;         // 115184
constexpr int OFF_MESH = OFF_IS + kB * kM;        // 197600

__device__ __forceinline__ float exp2_fast(float x){ return __builtin_amdgcn_exp2f(x); }
__device__ __forceinline__ float rcp_fast(float x){ return __builtin_amdgcn_rcpf(x); }

// ---- encoder context: ctx = masked-mean(relu(enc_in @ Ws + bs)); ctxW = ctx @ Wc
__global__ __launch_bounds__(256) void k_enc(const float* __restrict__ enc_in,
        const float* __restrict__ mask, const float* __restrict__ Ws,
        const float* __restrict__ bs, const float* __restrict__ Wc,
        float* __restrict__ ctxW, float* __restrict__ dsum){
    __shared__ float ctx_l[kH];
    int b = blockIdx.x, h = threadIdx.x;
    if (b == 0 && h == 0) dsum[0] = 0.f;  // zero accumulator for k_dens (later on same stream)
    float w0 = Ws[h], w1 = Ws[kH + h], bh = bs[h];
    float acc = 0.f, msum = 0.f;
    const float* e = enc_in + b * kS * 2;
    const float* mk = mask + b * kS;
    for (int s = 0; s < kS; ++s){
        float e0 = e[2*s], e1 = e[2*s+1], mm = mk[s];
        float v = fmaxf(fmaf(e0, w0, fmaf(e1, w1, bh)), 0.f);
        acc = fmaf(v, mm, acc);
        msum += mm;
    }
    ctx_l[h] = acc / fmaxf(msum, 1.f);
    __syncthreads();
    float o = 0.f;
    for (int k = 0; k < kH; ++k) o = fmaf(ctx_l[k], Wc[k * kH + h], o);
    ctxW[b * kH + h] = o;
}

// ---- density MLP input layer: x0 = relu(mesh @ Win + bin), batch-independent
__global__ __launch_bounds__(256) void k_mlp_in(const float* __restrict__ mesh,
        const float* __restrict__ Win, const float* __restrict__ bin,
        float* __restrict__ x0){
    int j = blockIdx.x, h = threadIdx.x;
    float be = mesh[2*j], al = mesh[2*j+1];
    x0[j * kH + h] = fmaxf(fmaf(be, Win[h], fmaf(al, Win[kH + h], bin[h])), 0.f);
}

// ---- residual layer: xout = xin + relu(xin @ W + b). Tiled fp32 GEMM.
// block: 64 points x 64 outs, thread: 8 points x 2 outs, K-slabs of 64 in LDS.
__global__ __launch_bounds__(256) void k_res(const float* __restrict__ xin,
        const float* __restrict__ Wl, const float* __restrict__ bl,
        float* __restrict__ xout){
    __shared__ float xT[64 * 68];   // [k][j], padded stride 68
    __shared__ float Wsh[64 * 68];  // [k][o], padded stride 68
    int tid = threadIdx.x;
    int og = tid & 31, pg = tid >> 5;       // out-group, point-group
    int jb = blockIdx.x * 64;               // 81 blocks
    int ob = blockIdx.y * 64;               // 4 blocks
    float acc[8][2] = {};
    for (int sl = 0; sl < 4; ++sl){
        int kb = sl * 64;
        #pragma unroll
        for (int it = 0; it < 16; ++it){
            int idx = tid + it * 256;
            int k = idx & 63, j = idx >> 6;
            int jg = jb + j;
            xT[k * 68 + j] = (jg < kM) ? xin[jg * kH + kb + k] : 0.f;
        }
        #pragma unroll
        for (int it = 0; it < 16; ++it){
            int idx = tid + it * 256;
            int o = idx & 63, k = idx >> 6;
            Wsh[k * 68 + o] = Wl[(kb + k) * kH + ob + o];
        }
        __syncthreads();
        #pragma unroll 2
        for (int k = 0; k < 64; ++k){
            float xv[8];
            *(float4*)&xv[0] = *(const float4*)&xT[k * 68 + pg * 8];
            *(float4*)&xv[4] = *(const float4*)&xT[k * 68 + pg * 8 + 4];
            float w0 = Wsh[k * 68 + og];
            float w1 = Wsh[k * 68 + og + 32];
            #pragma unroll
            for (int i = 0; i < 8; ++i){
                acc[i][0] = fmaf(xv[i], w0, acc[i][0]);
                acc[i][1] = fmaf(xv[i], w1, acc[i][1]);
            }
        }
        __syncthreads();
    }
    #pragma unroll
    for (int i = 0; i < 8; ++i){
        int jg = jb + pg * 8 + i;
        if (jg >= kM) continue;
        #pragma unroll
        for (int r = 0; r < 2; ++r){
            int o = ob + og + 32 * r;
            float v = acc[i][r] + bl[o];
            xout[jg * kH + o] = xin[jg * kH + o] + fmaxf(v, 0.f);
        }
    }
}

// ---- density head: density_j = sigmoid(x_j . Wout + bout); dsum += density_j
__global__ __launch_bounds__(256) void k_dens(const float* __restrict__ x,
        const float* __restrict__ Wout, const float* __restrict__ bout,
        float* __restrict__ dens, float* __restrict__ dsum){
    __shared__ float red[4];
    int j = blockIdx.x, tid = threadIdx.x;
    float v = x[j * kH + tid] * Wout[tid];
    #pragma unroll
    for (int off = 32; off; off >>= 1) v += __shfl_down(v, off, 64);
    if ((tid & 63) == 0) red[tid >> 6] = v;
    __syncthreads();
    if (tid == 0){
        float s = red[0] + red[1] + red[2] + red[3] + bout[0];
        float d = 1.f / (1.f + expf(-s));
        dens[j] = d;
        atomicAdd(dsum, d);
    }
}

// ---- initial states: is = tanh(relu(mesh_feat @ Wm + ctxW + bm) @ Wo + bo)
__global__ __launch_bounds__(256) void k_init(const float* __restrict__ mesh,
        const float* __restrict__ dens, const float* __restrict__ Wm,
        const float* __restrict__ bm, const float* __restrict__ ctxW,
        const float* __restrict__ Wo, const float* __restrict__ bo,
        float* __restrict__ isf, float* __restrict__ out){
    int j = blockIdx.x * 256 + threadIdx.x;
    int b = blockIdx.y;
    if (j >= kM) return;
    float be = mesh[2*j], al = mesh[2*j+1], d = dens[j];
    const float* cw = ctxW + b * kH;
    float acc = 0.f;
    #pragma unroll 4
    for (int h = 0; h < kH; ++h){
        float pre = fmaf(be, Wm[h], fmaf(al, Wm[kH + h], fmaf(d, Wm[2*kH + h], bm[h] + cw[h])));
        acc = fmaf(fmaxf(pre, 0.f), Wo[h], acc);
    }
    float v = tanhf(acc + bo[0]);
    isf[b * kM + j] = v;
    out[OFF_IS + b * kM + j] = v;
}

// ---- relay scan: per-(b,j) independent across all T; per-wave reduce -> partials[b][wave][t]
__global__ __launch_bounds__(256) void k_scan(const float* __restrict__ mesh,
        const float* __restrict__ dens, const float* __restrict__ isf,
        const float* __restrict__ dec, float* __restrict__ partials,
        float* __restrict__ out){
    __shared__ float hs[kT];
    int tid = threadIdx.x;
    int b = blockIdx.y;
    int j = blockIdx.x * 256 + tid;
    bool valid = j < kM;
    float d  = valid ? dens[j] : 0.f;
    float s  = valid ? isf[b * kM + j] : 0.f;
    float beta_v  = valid ? mesh[2*j]   : 0.f;
    float alpha_v = valid ? mesh[2*j+1] : 0.f;
    float as  = alpha_v * kSig;   // alpha * 1000 * log2e
    float bs_ = beta_v * kSig;    // beta  * 1000 * log2e
    if (valid){
        // fused broadcast outputs (batch-identical density & mesh)
        out[OFF_DENS + b * kM + j] = d;
        out[OFF_MESH + 2 * (b * kM + j)]     = beta_v;
        out[OFF_MESH + 2 * (b * kM + j) + 1] = alpha_v;
    }
    const float* hb = dec + b * kT;
    for (int i = tid; i < kT; i += 256) hs[i] = hb[i] * kSig;
    __syncthreads();
    long widx = (long)(b * kWavesPerB + blockIdx.x * 4 + (tid >> 6)) * kT;
    #pragma unroll 4
    for (int t = 0; t < kT; ++t){
        float ht = hs[t];
        // w_up = sigmoid((ht-alpha)/TEMP) = 1/(1+2^(as-ht)); w_dn = 1/(1+2^(ht-bs_))
        float eu = exp2_fast(as - ht);
        float ed = exp2_fast(ht - bs_);
        float wu = rcp_fast(1.f + eu);
        float wd = rcp_fast(1.f + ed);
        s = fmaf(wu, 1.f - s, s);
        s = fmaf(wd, -1.f - s, s);
        float c = d * s;
        c += __shfl_down(c, 32, 64);
        c += __shfl_down(c, 16, 64);
        c += __shfl_down(c, 8, 64);
        c += __shfl_down(c, 4, 64);
        c += __shfl_down(c, 2, 64);
        c += __shfl_down(c, 1, 64);
        if ((tid & 63) == 0) partials[widx + t] = c;
    }
}

// ---- finalize: m = sum(partials)/dsum; b_out = h_scale*h + m_scale*m + m_offset
__global__ __launch_bounds__(256) void k_final(const float* __restrict__ partials,
        const float* __restrict__ dsum, const float* __restrict__ dec,
        const float* __restrict__ hsr, const float* __restrict__ msr,
        const float* __restrict__ mor, float* __restrict__ out){
    int t = blockIdx.x * 256 + threadIdx.x;   // grid.x = 4
    int b = blockIdx.y;
    float acc = 0.f;
    const float* p = partials + (long)b * kWavesPerB * kT + t;
    for (int w = 0; w < kWavesPerB; ++w) acc += p[(long)w * kT];
    float m = acc / dsum[0];
    float hscale = 10.f / (1.f + expf(-hsr[0]));           // [0,10]
    float mscale = 10.f / (1.f + expf(-msr[0]));           // [0,10]
    float moff   = -10.f + 20.f / (1.f + expf(-mor[0]));   // [-10,10]
    float h = dec[b * kT + t];
    out[OFF_M + b * kT + t]    = m;
    out[OFF_BOUT + b * kT + t] = fmaf(hscale, h, fmaf(mscale, m, moff));
}

extern "C" void kernel_launch(void* const* d_in, const int* in_sizes, int n_in,
                              void* d_out, int out_size, void* d_ws, size_t ws_size,
                              hipStream_t stream) {
    (void)in_sizes; (void)n_in; (void)out_size; (void)ws_size;
    const float* enc_in = (const float*)d_in[0];
    const float* dec    = (const float*)d_in[1];
    const float* mask   = (const float*)d_in[2];
    const float* mesh   = (const float*)d_in[3];
    const float* Win    = (const float*)d_in[4];
    const float* bin    = (const float*)d_in[5];
    const float* Wr     = (const float*)d_in[6];
    const float* br     = (const float*)d_in[7];
    const float* Wout   = (const float*)d_in[8];
    const float* bout   = (const float*)d_in[9];
    const float* Ws     = (const float*)d_in[10];
    const float* bs     = (const float*)d_in[11];
    const float* Wm     = (const float*)d_in[12];
    const float* Wc     = (const float*)d_in[13];
    const float* bm     = (const float*)d_in[14];
    const float* Wo     = (const float*)d_in[15];
    const float* bo     = (const float*)d_in[16];
    const float* hsr    = (const float*)d_in[17];
    const float* msr    = (const float*)d_in[18];
    const float* mor    = (const float*)d_in[19];
    float* out = (float*)d_out;

    float* ws   = (float*)d_ws;
    float* xA   = ws;                    // 1,318,912 floats (padded M*H)
    float* xB   = xA + 1318912;
    float* dens = xB + 1318912;          // 5376
    float* dsum = dens + 5376;           // 16
    float* ctxW = dsum + 16;             // 4096
    float* isf  = ctxW + 4096;           // 16*5151 (82416)
    float* partials = ws;                // alias over xA/xB head: dead after k_dens

    k_enc   <<<dim3(kB),          256, 0, stream>>>(enc_in, mask, Ws, bs, Wc, ctxW, dsum);
    k_mlp_in<<<dim3(kM),          256, 0, stream>>>(mesh, Win, bin, xA);
    k_res   <<<dim3(81, 4),       256, 0, stream>>>(xA, Wr,           br,       xB);
    k_res   <<<dim3(81, 4),       256, 0, stream>>>(xB, Wr + 65536,   br + 256, xA);
    k_res   <<<dim3(81, 4),       256, 0, stream>>>(xA, Wr + 131072,  br + 512, xB);
    k_dens  <<<dim3(kM),          256, 0, stream>>>(xB, Wout, bout, dens, dsum);
    k_init  <<<dim3(kChunks, kB), 256, 0, stream>>>(mesh, dens, Wm, bm, ctxW, Wo, bo, isf, out);
    k_scan  <<<dim3(kChunks, kB), 256, 0, stream>>>(mesh, dens, isf, dec, partials, out);
    k_final <<<dim3(4, kB),       256, 0, stream>>>(partials, dsum, dec, hsr, msr, mor, out);
}

// Round 5
// 427.430 us; speedup vs baseline: 1.4263x; 1.4263x over previous
//
#include <hip/hip_runtime.h>
#include <hip/hip_bf16.h>
#include <math.h>

constexpr int kB = 16;
constexpr int kS = 256;
constexpr int kT = 1024;
constexpr int kM = 5151;
constexpr int kH = 256;
constexpr int kG = 16;                   // t-chunks
constexpr int kL = 64;                   // t's per chunk
constexpr int kJW = 84;                  // ceil(M/64) j-waves
constexpr float kSig = 1442.6950408889634f; // 1000 * log2(e)
constexpr float kClamp = 1e16f;          // exp clamp: products stay < fp32 max (1e32)

constexpr int OFF_BOUT = 0;
constexpr int OFF_DENS = kB * kT;                 // 16384
constexpr int OFF_M    = OFF_DENS + kB * kM;      // 98800
constexpr int OFF_IS   = OFF_M + kB * kT;         // 115184
constexpr int OFF_MESH = OFF_IS + kB * kM;        // 197600

// workspace layout (floats). Proven ws >= 2729728 floats from R3's passing run.
constexpr int WS_S1   = 0;        // 1318656 = kM*kH : xA -> A -> sin
constexpr int WS_S2   = 1318656;  // 1318656         : xB -> C -> partials(bf16)
constexpr int WS_DENS = 2637312;  // 5376
constexpr int WS_DSUM = 2642688;  // 16
constexpr int WS_CTXW = 2642704;  // 4096
constexpr int WS_ISF  = 2646800;  // 82416 ; end 2729216 < 2729728 ok

__device__ __forceinline__ float exp2_fast(float x){ return __builtin_amdgcn_exp2f(x); }
__device__ __forceinline__ float rcp_fast(float x){ return __builtin_amdgcn_rcpf(x); }

// ---- encoder context: ctx = masked-mean(relu(enc_in @ Ws + bs)); ctxW = ctx @ Wc
__global__ __launch_bounds__(256) void k_enc(const float* __restrict__ enc_in,
        const float* __restrict__ mask, const float* __restrict__ Ws,
        const float* __restrict__ bs, const float* __restrict__ Wc,
        float* __restrict__ ctxW, float* __restrict__ dsum){
    __shared__ float ctx_l[kH];
    int b = blockIdx.x, h = threadIdx.x;
    if (b == 0 && h == 0) dsum[0] = 0.f;  // zero accumulator for k_dens (later on same stream)
    float w0 = Ws[h], w1 = Ws[kH + h], bh = bs[h];
    float acc = 0.f, msum = 0.f;
    const float* e = enc_in + b * kS * 2;
    const float* mk = mask + b * kS;
    #pragma unroll 4
    for (int s = 0; s < kS; ++s){
        float e0 = e[2*s], e1 = e[2*s+1], mm = mk[s];
        float v = fmaxf(fmaf(e0, w0, fmaf(e1, w1, bh)), 0.f);
        acc = fmaf(v, mm, acc);
        msum += mm;
    }
    ctx_l[h] = acc / fmaxf(msum, 1.f);
    __syncthreads();
    float o = 0.f;
    #pragma unroll 8
    for (int k = 0; k < kH; ++k) o = fmaf(ctx_l[k], Wc[k * kH + h], o);
    ctxW[b * kH + h] = o;
}

// ---- density MLP input layer: x0 = relu(mesh @ Win + bin), batch-independent
__global__ __launch_bounds__(256) void k_mlp_in(const float* __restrict__ mesh,
        const float* __restrict__ Win, const float* __restrict__ bin,
        float* __restrict__ x0){
    int j = blockIdx.x, h = threadIdx.x;
    float be = mesh[2*j], al = mesh[2*j+1];
    x0[j * kH + h] = fmaxf(fmaf(be, Win[h], fmaf(al, Win[kH + h], bin[h])), 0.f);
}

// ---- residual layer: xout = xin + relu(xin @ W + b). Tiled fp32 GEMM.
__global__ __launch_bounds__(256) void k_res(const float* __restrict__ xin,
        const float* __restrict__ Wl, const float* __restrict__ bl,
        float* __restrict__ xout){
    __shared__ float xT[64 * 68];   // [k][j], padded stride 68
    __shared__ float Wsh[64 * 68];  // [k][o], padded stride 68
    int tid = threadIdx.x;
    int og = tid & 31, pg = tid >> 5;       // out-group, point-group
    int jb = blockIdx.x * 64;               // 81 blocks
    int ob = blockIdx.y * 64;               // 4 blocks
    float acc[8][2] = {};
    for (int sl = 0; sl < 4; ++sl){
        int kb = sl * 64;
        #pragma unroll
        for (int it = 0; it < 16; ++it){
            int idx = tid + it * 256;
            int k = idx & 63, j = idx >> 6;
            int jg = jb + j;
            xT[k * 68 + j] = (jg < kM) ? xin[jg * kH + kb + k] : 0.f;
        }
        #pragma unroll
        for (int it = 0; it < 16; ++it){
            int idx = tid + it * 256;
            int o = idx & 63, k = idx >> 6;
            Wsh[k * 68 + o] = Wl[(kb + k) * kH + ob + o];
        }
        __syncthreads();
        #pragma unroll 2
        for (int k = 0; k < 64; ++k){
            float xv[8];
            *(float4*)&xv[0] = *(const float4*)&xT[k * 68 + pg * 8];
            *(float4*)&xv[4] = *(const float4*)&xT[k * 68 + pg * 8 + 4];
            float w0 = Wsh[k * 68 + og];
            float w1 = Wsh[k * 68 + og + 32];
            #pragma unroll
            for (int i = 0; i < 8; ++i){
                acc[i][0] = fmaf(xv[i], w0, acc[i][0]);
                acc[i][1] = fmaf(xv[i], w1, acc[i][1]);
            }
        }
        __syncthreads();
    }
    #pragma unroll
    for (int i = 0; i < 8; ++i){
        int jg = jb + pg * 8 + i;
        if (jg >= kM) continue;
        #pragma unroll
        for (int r = 0; r < 2; ++r){
            int o = ob + og + 32 * r;
            float v = acc[i][r] + bl[o];
            xout[jg * kH + o] = xin[jg * kH + o] + fmaxf(v, 0.f);
        }
    }
}

// ---- density head: density_j = sigmoid(x_j . Wout + bout); dsum += density_j
__global__ __launch_bounds__(256) void k_dens(const float* __restrict__ x,
        const float* __restrict__ Wout, const float* __restrict__ bout,
        float* __restrict__ dens, float* __restrict__ dsum){
    __shared__ float red[4];
    int j = blockIdx.x, tid = threadIdx.x;
    float v = x[j * kH + tid] * Wout[tid];
    #pragma unroll
    for (int off = 32; off; off >>= 1) v += __shfl_down(v, off, 64);
    if ((tid & 63) == 0) red[tid >> 6] = v;
    __syncthreads();
    if (tid == 0){
        float s = red[0] + red[1] + red[2] + red[3] + bout[0];
        float d = 1.f / (1.f + expf(-s));
        dens[j] = d;
        atomicAdd(dsum, d);
    }
}

// ---- initial states: is = tanh(relu(mesh_feat @ Wm + ctxW + bm) @ Wo + bo)
__global__ __launch_bounds__(256) void k_init(const float* __restrict__ mesh,
        const float* __restrict__ dens, const float* __restrict__ Wm,
        const float* __restrict__ bm, const float* __restrict__ ctxW,
        const float* __restrict__ Wo, const float* __restrict__ bo,
        float* __restrict__ isf, float* __restrict__ out){
    __shared__ float w0s[kH], w1s[kH], w2s[kH], bcs[kH], wos[kH];
    int tid = threadIdx.x;
    int b = blockIdx.y;
    w0s[tid] = Wm[tid];
    w1s[tid] = Wm[kH + tid];
    w2s[tid] = Wm[2*kH + tid];
    bcs[tid] = bm[tid] + ctxW[b * kH + tid];
    wos[tid] = Wo[tid];
    __syncthreads();
    int j = blockIdx.x * 256 + tid;
    if (j >= kM) return;
    float be = mesh[2*j], al = mesh[2*j+1], d = dens[j];
    float acc = 0.f;
    #pragma unroll 8
    for (int h = 0; h < kH; ++h){
        float pre = fmaf(be, w0s[h], fmaf(al, w1s[h], fmaf(d, w2s[h], bcs[h])));
        acc = fmaf(fmaxf(pre, 0.f), wos[h], acc);
    }
    float v = tanhf(acc + bo[0]);
    isf[b * kM + j] = v;
    out[OFF_IS + b * kM + j] = v;
}

// ---- scan pass 1: per (b, j, chunk) affine coefficients (A, C) over 64 t-steps.
// one t-step: s' = (eu*ed*s + ed - eu - 1) / ((1+eu)(1+ed)); affine compose.
__global__ __launch_bounds__(256) void k_scanA(const float* __restrict__ mesh,
        const float* __restrict__ dec, float* __restrict__ A, float* __restrict__ C){
    __shared__ float hsl[kL];
    int tid = threadIdx.x;
    int g = blockIdx.y, b = blockIdx.z;
    if (tid < kL) hsl[tid] = dec[b * kT + g * kL + tid] * kSig;
    __syncthreads();
    int j = blockIdx.x * 256 + tid;
    bool valid = j < kM;
    float as  = valid ? mesh[2*j+1] * kSig : 0.f;
    float bs_ = valid ? mesh[2*j]   * kSig : 0.f;
    float Aa = 1.f, Cc = 0.f;
    #pragma unroll 4
    for (int t = 0; t < kL; ++t){
        float ht = hsl[t];
        float eu = fminf(exp2_fast(as - ht), kClamp);
        float ed = fminf(exp2_fast(ht - bs_), kClamp);
        float E  = eu * ed;                       // <= 1e32, finite
        float rD = rcp_fast((1.f + eu) * (1.f + ed));
        float a  = E * rD;
        float c  = (ed - eu - 1.f) * rD;
        Aa = a * Aa;
        Cc = fmaf(a, Cc, c);
    }
    if (valid){
        int idx = (g * kB + b) * kM + j;
        A[idx] = Aa;
        C[idx] = Cc;
    }
}

// ---- scan pass 2a: serial compose over 16 chunks; writes chunk ENTRY state into A (in-place).
__global__ __launch_bounds__(256) void k_scanB(const float* __restrict__ isf,
        float* __restrict__ A, const float* __restrict__ C){
    int j = blockIdx.x * 256 + threadIdx.x;
    int b = blockIdx.y;
    if (j >= kM) return;
    float s = isf[b * kM + j];
    #pragma unroll
    for (int g = 0; g < kG; ++g){
        int idx = (g * kB + b) * kM + j;
        float a = A[idx], c = C[idx];
        A[idx] = s;                 // entry state for chunk g
        s = fmaf(a, s, c);
    }
}

// ---- scan pass 2b: re-run each chunk from its entry state; LDS-transpose reduction:
// lane L ends up with the wave's 64-point partial for t = g*64+L. one bf16 store per wave.
__global__ __launch_bounds__(64) void k_scanC(const float* __restrict__ mesh,
        const float* __restrict__ dens, const float* __restrict__ sin_,
        const float* __restrict__ dec, __hip_bfloat16* __restrict__ partials,
        float* __restrict__ out){
    __shared__ float cb[kL * 65];
    __shared__ float hsl[kL];
    int L = threadIdx.x;
    int jw = blockIdx.x, g = blockIdx.y, b = blockIdx.z;
    int j = jw * 64 + L;
    hsl[L] = dec[b * kT + g * kL + L] * kSig;
    bool valid = j < kM;
    float d   = valid ? dens[j] : 0.f;
    float s   = valid ? sin_[(g * kB + b) * kM + j] : 0.f;
    float be  = valid ? mesh[2*j]   : 0.f;
    float al  = valid ? mesh[2*j+1] : 0.f;
    float as  = al * kSig;
    float bs_ = be * kSig;
    if (valid && g == 0){
        // fused broadcast outputs (batch-identical density & mesh)
        out[OFF_DENS + b * kM + j] = d;
        out[OFF_MESH + 2 * (b * kM + j)]     = be;
        out[OFF_MESH + 2 * (b * kM + j) + 1] = al;
    }
    __syncthreads();
    #pragma unroll 4
    for (int t = 0; t < kL; ++t){
        float ht = hsl[t];
        float eu = fminf(exp2_fast(as - ht), kClamp);
        float ed = fminf(exp2_fast(ht - bs_), kClamp);
        float E  = eu * ed;                       // <= 1e32, finite
        float rD = rcp_fast((1.f + eu) * (1.f + ed));
        s = fmaf(E, s, ed - eu - 1.f) * rD;
        cb[t * 65 + L] = d * s;
    }
    __syncthreads();
    float a0 = 0.f, a1 = 0.f;
    #pragma unroll
    for (int i = 0; i < kL; i += 2){
        a0 += cb[L * 65 + i];
        a1 += cb[L * 65 + i + 1];
    }
    partials[(b * kJW + jw) * kT + g * kL + L] = __float2bfloat16(a0 + a1);
}

// ---- finalize: m = sum(partials)/dsum; b_out = h_scale*h + m_scale*m + m_offset
__global__ __launch_bounds__(256) void k_final(const __hip_bfloat16* __restrict__ partials,
        const float* __restrict__ dsum, const float* __restrict__ dec,
        const float* __restrict__ hsr, const float* __restrict__ msr,
        const float* __restrict__ mor, float* __restrict__ out){
    int t = blockIdx.x * 256 + threadIdx.x;   // grid.x = 4
    int b = blockIdx.y;
    float acc = 0.f;
    const __hip_bfloat16* p = partials + (long)b * kJW * kT + t;
    #pragma unroll 4
    for (int w = 0; w < kJW; ++w) acc += __bfloat162float(p[(long)w * kT]);
    float m = acc / dsum[0];
    float hscale = 10.f / (1.f + expf(-hsr[0]));           // [0,10]
    float mscale = 10.f / (1.f + expf(-msr[0]));           // [0,10]
    float moff   = -10.f + 20.f / (1.f + expf(-mor[0]));   // [-10,10]
    float h = dec[b * kT + t];
    out[OFF_M + b * kT + t]    = m;
    out[OFF_BOUT + b * kT + t] = fmaf(hscale, h, fmaf(mscale, m, moff));
}

extern "C" void kernel_launch(void* const* d_in, const int* in_sizes, int n_in,
                              void* d_out, int out_size, void* d_ws, size_t ws_size,
                              hipStream_t stream) {
    (void)in_sizes; (void)n_in; (void)out_size; (void)ws_size;
    const float* enc_in = (const float*)d_in[0];
    const float* dec    = (const float*)d_in[1];
    const float* mask   = (const float*)d_in[2];
    const float* mesh   = (const float*)d_in[3];
    const float* Win    = (const float*)d_in[4];
    const float* bin    = (const float*)d_in[5];
    const float* Wr     = (const float*)d_in[6];
    const float* br     = (const float*)d_in[7];
    const float* Wout   = (const float*)d_in[8];
    const float* bout   = (const float*)d_in[9];
    const float* Ws     = (const float*)d_in[10];
    const float* bs     = (const float*)d_in[11];
    const float* Wm     = (const float*)d_in[12];
    const float* Wc     = (const float*)d_in[13];
    const float* bm     = (const float*)d_in[14];
    const float* Wo     = (const float*)d_in[15];
    const float* bo     = (const float*)d_in[16];
    const float* hsr    = (const float*)d_in[17];
    const float* msr    = (const float*)d_in[18];
    const float* mor    = (const float*)d_in[19];
    float* out = (float*)d_out;

    float* ws   = (float*)d_ws;
    float* S1   = ws + WS_S1;     // xA -> A -> sin
    float* S2   = ws + WS_S2;     // xB -> C -> partials(bf16)
    float* dens = ws + WS_DENS;
    float* dsum = ws + WS_DSUM;
    float* ctxW = ws + WS_CTXW;
    float* isf  = ws + WS_ISF;
    __hip_bfloat16* partials = (__hip_bfloat16*)S2;

    k_enc   <<<dim3(kB),           256, 0, stream>>>(enc_in, mask, Ws, bs, Wc, ctxW, dsum);
    k_mlp_in<<<dim3(kM),           256, 0, stream>>>(mesh, Win, bin, S1);
    k_res   <<<dim3(81, 4),        256, 0, stream>>>(S1, Wr,           br,       S2);
    k_res   <<<dim3(81, 4),        256, 0, stream>>>(S2, Wr + 65536,   br + 256, S1);
    k_res   <<<dim3(81, 4),        256, 0, stream>>>(S1, Wr + 131072,  br + 512, S2);
    k_dens  <<<dim3(kM),           256, 0, stream>>>(S2, Wout, bout, dens, dsum);
    k_init  <<<dim3(21, kB),       256, 0, stream>>>(mesh, dens, Wm, bm, ctxW, Wo, bo, isf, out);
    k_scanA <<<dim3(21, kG, kB),   256, 0, stream>>>(mesh, dec, S1, S2);
    k_scanB <<<dim3(21, kB),       256, 0, stream>>>(isf, S1, S2);
    k_scanC <<<dim3(kJW, kG, kB),   64, 0, stream>>>(mesh, dens, S1, dec, partials, out);
    k_final <<<dim3(4, kB),        256, 0, stream>>>(partials, dsum, dec, hsr, msr, mor, out);
}

// Round 6
// 357.853 us; speedup vs baseline: 1.7036x; 1.1944x over previous
//
#include <hip/hip_runtime.h>
#include <hip/hip_bf16.h>
#include <math.h>

constexpr int kB = 16;
constexpr int kS = 256;
constexpr int kT = 1024;
constexpr int kM = 5151;
constexpr int kH = 256;
constexpr int kG = 16;                   // t-chunks
constexpr int kL = 64;                   // t's per chunk
constexpr int kJW = 84;                  // ceil(M/64) j-waves
constexpr float kSig = 1442.6950408889634f; // 1000 * log2(e)
constexpr float kClamp = 1e16f;          // exp clamp: products stay < fp32 max (1e32)

constexpr int OFF_BOUT = 0;
constexpr int OFF_DENS = kB * kT;                 // 16384
constexpr int OFF_M    = OFF_DENS + kB * kM;      // 98800
constexpr int OFF_IS   = OFF_M + kB * kT;         // 115184
constexpr int OFF_MESH = OFF_IS + kB * kM;        // 197600

// workspace layout (floats). Proven ws >= 2729728 floats from R3's passing run.
constexpr int WS_S1   = 0;        // 1318656 = kG*kB*kM : xA/x3 -> A -> entry states
constexpr int WS_S2   = 1318656;  // 1318656            : xB -> C -> partials(bf16)
constexpr int WS_DENS = 2637312;  // 5376
constexpr int WS_CTXW = 2642704;  // 4096  (end 2646800 < 2729728 ok)

__device__ __forceinline__ float exp2_fast(float x){ return __builtin_amdgcn_exp2f(x); }
__device__ __forceinline__ float rcp_fast(float x){ return __builtin_amdgcn_rcpf(x); }

// ---- encoder context: ctx = masked-mean(relu(enc_in @ Ws + bs)); ctxW = ctx @ Wc
__global__ __launch_bounds__(256) void k_enc(const float* __restrict__ enc_in,
        const float* __restrict__ mask, const float* __restrict__ Ws,
        const float* __restrict__ bs, const float* __restrict__ Wc,
        float* __restrict__ ctxW){
    __shared__ float ctx_l[kH];
    int b = blockIdx.x, h = threadIdx.x;
    float w0 = Ws[h], w1 = Ws[kH + h], bh = bs[h];
    float acc = 0.f, msum = 0.f;
    const float* e = enc_in + b * kS * 2;
    const float* mk = mask + b * kS;
    #pragma unroll 4
    for (int s = 0; s < kS; ++s){
        float e0 = e[2*s], e1 = e[2*s+1], mm = mk[s];
        float v = fmaxf(fmaf(e0, w0, fmaf(e1, w1, bh)), 0.f);
        acc = fmaf(v, mm, acc);
        msum += mm;
    }
    ctx_l[h] = acc / fmaxf(msum, 1.f);
    __syncthreads();
    float o = 0.f;
    #pragma unroll 8
    for (int k = 0; k < kH; ++k) o = fmaf(ctx_l[k], Wc[k * kH + h], o);
    ctxW[b * kH + h] = o;
}

// ---- first residual layer, fused with the input layer:
// x0 = relu(mesh @ Win + bin) computed on the fly; xout = x0 + relu(x0 @ W + b)
__global__ __launch_bounds__(256) void k_res_first(const float* __restrict__ mesh,
        const float* __restrict__ Win, const float* __restrict__ bin,
        const float* __restrict__ Wl, const float* __restrict__ bl,
        float* __restrict__ xout){
    __shared__ float xT[64 * 68];   // [k][j], padded stride 68
    __shared__ float Wsh[64 * 68];  // [k][o], padded stride 68
    __shared__ float beL[64], alL[64];
    int tid = threadIdx.x;
    int og = tid & 31, pg = tid >> 5;
    int jb = blockIdx.x * 64;
    int ob = blockIdx.y * 64;
    if (tid < 64){
        int jg = jb + tid;
        beL[tid] = (jg < kM) ? mesh[2*jg]   : 0.f;
        alL[tid] = (jg < kM) ? mesh[2*jg+1] : 0.f;
    }
    __syncthreads();
    float acc[8][2] = {};
    for (int sl = 0; sl < 4; ++sl){
        int kb = sl * 64;
        #pragma unroll
        for (int it = 0; it < 16; ++it){
            int idx = tid + it * 256;
            int k = idx & 63, j = idx >> 6;
            // x0[j][kb+k] computed on the fly (same fmaf order as reference path)
            xT[k * 68 + j] = fmaxf(fmaf(beL[j], Win[kb + k],
                              fmaf(alL[j], Win[kH + kb + k], bin[kb + k])), 0.f);
        }
        #pragma unroll
        for (int it = 0; it < 16; ++it){
            int idx = tid + it * 256;
            int o = idx & 63, k = idx >> 6;
            Wsh[k * 68 + o] = Wl[(kb + k) * kH + ob + o];
        }
        __syncthreads();
        #pragma unroll 2
        for (int k = 0; k < 64; ++k){
            float xv[8];
            *(float4*)&xv[0] = *(const float4*)&xT[k * 68 + pg * 8];
            *(float4*)&xv[4] = *(const float4*)&xT[k * 68 + pg * 8 + 4];
            float w0 = Wsh[k * 68 + og];
            float w1 = Wsh[k * 68 + og + 32];
            #pragma unroll
            for (int i = 0; i < 8; ++i){
                acc[i][0] = fmaf(xv[i], w0, acc[i][0]);
                acc[i][1] = fmaf(xv[i], w1, acc[i][1]);
            }
        }
        __syncthreads();
    }
    #pragma unroll
    for (int i = 0; i < 8; ++i){
        int jg = jb + pg * 8 + i;
        if (jg >= kM) continue;
        float be = beL[pg * 8 + i], al = alL[pg * 8 + i];
        #pragma unroll
        for (int r = 0; r < 2; ++r){
            int o = ob + og + 32 * r;
            float x0v = fmaxf(fmaf(be, Win[o], fmaf(al, Win[kH + o], bin[o])), 0.f);
            float v = acc[i][r] + bl[o];
            xout[jg * kH + o] = x0v + fmaxf(v, 0.f);
        }
    }
}

// ---- residual layer: xout = xin + relu(xin @ W + b). Tiled fp32 GEMM.
__global__ __launch_bounds__(256) void k_res(const float* __restrict__ xin,
        const float* __restrict__ Wl, const float* __restrict__ bl,
        float* __restrict__ xout){
    __shared__ float xT[64 * 68];
    __shared__ float Wsh[64 * 68];
    int tid = threadIdx.x;
    int og = tid & 31, pg = tid >> 5;
    int jb = blockIdx.x * 64;
    int ob = blockIdx.y * 64;
    float acc[8][2] = {};
    for (int sl = 0; sl < 4; ++sl){
        int kb = sl * 64;
        #pragma unroll
        for (int it = 0; it < 16; ++it){
            int idx = tid + it * 256;
            int k = idx & 63, j = idx >> 6;
            int jg = jb + j;
            xT[k * 68 + j] = (jg < kM) ? xin[jg * kH + kb + k] : 0.f;
        }
        #pragma unroll
        for (int it = 0; it < 16; ++it){
            int idx = tid + it * 256;
            int o = idx & 63, k = idx >> 6;
            Wsh[k * 68 + o] = Wl[(kb + k) * kH + ob + o];
        }
        __syncthreads();
        #pragma unroll 2
        for (int k = 0; k < 64; ++k){
            float xv[8];
            *(float4*)&xv[0] = *(const float4*)&xT[k * 68 + pg * 8];
            *(float4*)&xv[4] = *(const float4*)&xT[k * 68 + pg * 8 + 4];
            float w0 = Wsh[k * 68 + og];
            float w1 = Wsh[k * 68 + og + 32];
            #pragma unroll
            for (int i = 0; i < 8; ++i){
                acc[i][0] = fmaf(xv[i], w0, acc[i][0]);
                acc[i][1] = fmaf(xv[i], w1, acc[i][1]);
            }
        }
        __syncthreads();
    }
    #pragma unroll
    for (int i = 0; i < 8; ++i){
        int jg = jb + pg * 8 + i;
        if (jg >= kM) continue;
        #pragma unroll
        for (int r = 0; r < 2; ++r){
            int o = ob + og + 32 * r;
            float v = acc[i][r] + bl[o];
            xout[jg * kH + o] = xin[jg * kH + o] + fmaxf(v, 0.f);
        }
    }
}

// ---- density head: density_j = sigmoid(x_j . Wout + bout). No atomics.
__global__ __launch_bounds__(256) void k_dens(const float* __restrict__ x,
        const float* __restrict__ Wout, const float* __restrict__ bout,
        float* __restrict__ dens){
    __shared__ float red[4];
    int j = blockIdx.x, tid = threadIdx.x;
    float v = x[j * kH + tid] * Wout[tid];
    #pragma unroll
    for (int off = 32; off; off >>= 1) v += __shfl_down(v, off, 64);
    if ((tid & 63) == 0) red[tid >> 6] = v;
    __syncthreads();
    if (tid == 0){
        float s = red[0] + red[1] + red[2] + red[3] + bout[0];
        dens[j] = 1.f / (1.f + expf(-s));
    }
}

// ---- scan pass 1: per (b, j, chunk) affine coefficients (A, C) over 64 t-steps.
__global__ __launch_bounds__(256) void k_scanA(const float* __restrict__ mesh,
        const float* __restrict__ dec, float* __restrict__ A, float* __restrict__ C){
    __shared__ float hsl[kL];
    int tid = threadIdx.x;
    int g = blockIdx.y, b = blockIdx.z;
    if (tid < kL) hsl[tid] = dec[b * kT + g * kL + tid] * kSig;
    __syncthreads();
    int j = blockIdx.x * 256 + tid;
    bool valid = j < kM;
    float as  = valid ? mesh[2*j+1] * kSig : 0.f;
    float bs_ = valid ? mesh[2*j]   * kSig : 0.f;
    float Aa = 1.f, Cc = 0.f;
    #pragma unroll 4
    for (int t = 0; t < kL; ++t){
        float ht = hsl[t];
        float eu = fminf(exp2_fast(as - ht), kClamp);
        float ed = fminf(exp2_fast(ht - bs_), kClamp);
        float E  = eu * ed;                       // <= 1e32, finite
        float rD = rcp_fast((1.f + eu) * (1.f + ed));
        float a  = E * rD;
        float c  = (ed - eu - 1.f) * rD;
        Aa = a * Aa;
        Cc = fmaf(a, Cc, c);
    }
    if (valid){
        int idx = (g * kB + b) * kM + j;
        A[idx] = Aa;
        C[idx] = Cc;
    }
}

// ---- initial states + chunk compose (fused): is = tanh(relu(mesh_feat@Wm+ctxW+bm)@Wo+bo),
// then serially compose 16 chunk-affines, writing each chunk's ENTRY state into A in place.
__global__ __launch_bounds__(256) void k_initB(const float* __restrict__ mesh,
        const float* __restrict__ dens, const float* __restrict__ Wm,
        const float* __restrict__ bm, const float* __restrict__ ctxW,
        const float* __restrict__ Wo, const float* __restrict__ bo,
        float* __restrict__ A, const float* __restrict__ C,
        float* __restrict__ out){
    __shared__ float w0s[kH], w1s[kH], w2s[kH], bcs[kH], wos[kH];
    int tid = threadIdx.x;
    int b = blockIdx.y;
    w0s[tid] = Wm[tid];
    w1s[tid] = Wm[kH + tid];
    w2s[tid] = Wm[2*kH + tid];
    bcs[tid] = bm[tid] + ctxW[b * kH + tid];
    wos[tid] = Wo[tid];
    __syncthreads();
    int j = blockIdx.x * 256 + tid;
    if (j >= kM) return;
    float be = mesh[2*j], al = mesh[2*j+1], d = dens[j];
    float acc = 0.f;
    #pragma unroll 8
    for (int h = 0; h < kH; ++h){
        float pre = fmaf(be, w0s[h], fmaf(al, w1s[h], fmaf(d, w2s[h], bcs[h])));
        acc = fmaf(fmaxf(pre, 0.f), wos[h], acc);
    }
    float s = tanhf(acc + bo[0]);
    out[OFF_IS + b * kM + j] = s;
    #pragma unroll
    for (int g = 0; g < kG; ++g){
        int idx = (g * kB + b) * kM + j;
        float a = A[idx], c = C[idx];
        A[idx] = s;                 // entry state for chunk g
        s = fmaf(a, s, c);
    }
}

// ---- scan pass 2b: re-run each chunk from its entry state; LDS-transpose reduction:
// lane L ends up with the wave's 64-point partial for t = g*64+L. one bf16 store per wave.
__global__ __launch_bounds__(64) void k_scanC(const float* __restrict__ mesh,
        const float* __restrict__ dens, const float* __restrict__ sin_,
        const float* __restrict__ dec, __hip_bfloat16* __restrict__ partials,
        float* __restrict__ out){
    __shared__ float cb[kL * 65];
    __shared__ float hsl[kL];
    int L = threadIdx.x;
    int jw = blockIdx.x, g = blockIdx.y, b = blockIdx.z;
    int j = jw * 64 + L;
    hsl[L] = dec[b * kT + g * kL + L] * kSig;
    bool valid = j < kM;
    float d   = valid ? dens[j] : 0.f;
    float s   = valid ? sin_[(g * kB + b) * kM + j] : 0.f;
    float be  = valid ? mesh[2*j]   : 0.f;
    float al  = valid ? mesh[2*j+1] : 0.f;
    float as  = al * kSig;
    float bs_ = be * kSig;
    if (valid && g == 0){
        // fused broadcast outputs (batch-identical density & mesh)
        out[OFF_DENS + b * kM + j] = d;
        out[OFF_MESH + 2 * (b * kM + j)]     = be;
        out[OFF_MESH + 2 * (b * kM + j) + 1] = al;
    }
    __syncthreads();
    #pragma unroll 4
    for (int t = 0; t < kL; ++t){
        float ht = hsl[t];
        float eu = fminf(exp2_fast(as - ht), kClamp);
        float ed = fminf(exp2_fast(ht - bs_), kClamp);
        float E  = eu * ed;
        float rD = rcp_fast((1.f + eu) * (1.f + ed));
        s = fmaf(E, s, ed - eu - 1.f) * rD;
        cb[t * 65 + L] = d * s;
    }
    __syncthreads();
    float a0 = 0.f, a1 = 0.f;
    #pragma unroll
    for (int i = 0; i < kL; i += 2){
        a0 += cb[L * 65 + i];
        a1 += cb[L * 65 + i + 1];
    }
    partials[(b * kJW + jw) * kT + g * kL + L] = __float2bfloat16(a0 + a1);
}

// ---- finalize: dsum reduced per-block (redundant, cheap); m = sum(partials)/dsum;
// b_out = h_scale*h + m_scale*m + m_offset
__global__ __launch_bounds__(256) void k_final(const __hip_bfloat16* __restrict__ partials,
        const float* __restrict__ dens, const float* __restrict__ dec,
        const float* __restrict__ hsr, const float* __restrict__ msr,
        const float* __restrict__ mor, float* __restrict__ out){
    __shared__ float red[4];
    int tid = threadIdx.x;
    int b = blockIdx.y;
    float ds = 0.f;
    for (int i = tid; i < kM; i += 256) ds += dens[i];
    #pragma unroll
    for (int off = 32; off; off >>= 1) ds += __shfl_down(ds, off, 64);
    if ((tid & 63) == 0) red[tid >> 6] = ds;
    __syncthreads();
    float dsum = red[0] + red[1] + red[2] + red[3];
    int t = blockIdx.x * 256 + tid;   // grid.x = 4
    float acc = 0.f;
    const __hip_bfloat16* p = partials + (long)b * kJW * kT + t;
    #pragma unroll 4
    for (int w = 0; w < kJW; ++w) acc += __bfloat162float(p[(long)w * kT]);
    float m = acc / dsum;
    float hscale = 10.f / (1.f + expf(-hsr[0]));           // [0,10]
    float mscale = 10.f / (1.f + expf(-msr[0]));           // [0,10]
    float moff   = -10.f + 20.f / (1.f + expf(-mor[0]));   // [-10,10]
    float h = dec[b * kT + t];
    out[OFF_M + b * kT + t]    = m;
    out[OFF_BOUT + b * kT + t] = fmaf(hscale, h, fmaf(mscale, m, moff));
}

extern "C" void kernel_launch(void* const* d_in, const int* in_sizes, int n_in,
                              void* d_out, int out_size, void* d_ws, size_t ws_size,
                              hipStream_t stream) {
    (void)in_sizes; (void)n_in; (void)out_size; (void)ws_size;
    const float* enc_in = (const float*)d_in[0];
    const float* dec    = (const float*)d_in[1];
    const float* mask   = (const float*)d_in[2];
    const float* mesh   = (const float*)d_in[3];
    const float* Win    = (const float*)d_in[4];
    const float* bin    = (const float*)d_in[5];
    const float* Wr     = (const float*)d_in[6];
    const float* br     = (const float*)d_in[7];
    const float* Wout   = (const float*)d_in[8];
    const float* bout   = (const float*)d_in[9];
    const float* Ws     = (const float*)d_in[10];
    const float* bs     = (const float*)d_in[11];
    const float* Wm     = (const float*)d_in[12];
    const float* Wc     = (const float*)d_in[13];
    const float* bm     = (const float*)d_in[14];
    const float* Wo     = (const float*)d_in[15];
    const float* bo     = (const float*)d_in[16];
    const float* hsr    = (const float*)d_in[17];
    const float* msr    = (const float*)d_in[18];
    const float* mor    = (const float*)d_in[19];
    float* out = (float*)d_out;

    float* ws   = (float*)d_ws;
    float* S1   = ws + WS_S1;     // x1/x3 -> A -> entry states
    float* S2   = ws + WS_S2;     // x2 -> C -> partials(bf16)
    float* dens = ws + WS_DENS;
    float* ctxW = ws + WS_CTXW;
    __hip_bfloat16* partials = (__hip_bfloat16*)S2;

    k_enc      <<<dim3(kB),         256, 0, stream>>>(enc_in, mask, Ws, bs, Wc, ctxW);
    k_res_first<<<dim3(81, 4),      256, 0, stream>>>(mesh, Win, bin, Wr, br, S1);
    k_res      <<<dim3(81, 4),      256, 0, stream>>>(S1, Wr + 65536,  br + 256, S2);
    k_res      <<<dim3(81, 4),      256, 0, stream>>>(S2, Wr + 131072, br + 512, S1);
    k_dens     <<<dim3(kM),         256, 0, stream>>>(S1, Wout, bout, dens);
    k_scanA    <<<dim3(21, kG, kB), 256, 0, stream>>>(mesh, dec, S1, S2);  // S1/S2 dead as x now
    k_initB    <<<dim3(21, kB),     256, 0, stream>>>(mesh, dens, Wm, bm, ctxW, Wo, bo, S1, S2, out);
    k_scanC    <<<dim3(kJW, kG, kB), 64, 0, stream>>>(mesh, dens, S1, dec, partials, out);
    k_final    <<<dim3(4, kB),      256, 0, stream>>>(partials, dens, dec, hsr, msr, mor, out);
}

// Round 7
// 355.015 us; speedup vs baseline: 1.7172x; 1.0080x over previous
//
#include <hip/hip_runtime.h>
#include <hip/hip_bf16.h>
#include <math.h>

constexpr int kB = 16;
constexpr int kS = 256;
constexpr int kT = 1024;
constexpr int kM = 5151;
constexpr int kH = 256;
constexpr int kG = 16;                   // t-chunks
constexpr int kL = 64;                   // t's per chunk
constexpr int kJW = 84;                  // ceil(M/64) j-waves
constexpr float kSig = 1442.6950408889634f; // 1000 * log2(e)
constexpr float kClamp = 1e16f;          // exp clamp: products stay < fp32 max (1e32)

constexpr int OFF_BOUT = 0;
constexpr int OFF_DENS = kB * kT;                 // 16384
constexpr int OFF_M    = OFF_DENS + kB * kM;      // 98800
constexpr int OFF_IS   = OFF_M + kB * kT;         // 115184
constexpr int OFF_MESH = OFF_IS + kB * kM;        // 197600

// workspace layout (floats). Proven ws >= 2729728 floats from R3's passing run.
constexpr int WS_S1    = 0;        // 1318656 = kG*kB*kM : x1/x3 -> A -> entry states
constexpr int WS_S2    = 1318656;  // 1318656            : x2 -> C -> partials(bf16)
constexpr int WS_DENS  = 2637312;  // 5376 (sigmoid'd density)
constexpr int WS_DENSP = 2642688;  // 5376 (pre-sigmoid logits, atomic accum)
constexpr int WS_CTXW  = 2648064;  // 4096  (end 2652160 < 2729728 ok)

__device__ __forceinline__ float exp2_fast(float x){ return __builtin_amdgcn_exp2f(x); }
__device__ __forceinline__ float rcp_fast(float x){ return __builtin_amdgcn_rcpf(x); }

// ---- encoder context: ctx = masked-mean(relu(enc_in @ Ws + bs)); ctxW = ctx @ Wc
// also zeroes dens_pre (stream-ordered before any accumulation).
__global__ __launch_bounds__(256) void k_enc(const float* __restrict__ enc_in,
        const float* __restrict__ mask, const float* __restrict__ Ws,
        const float* __restrict__ bs, const float* __restrict__ Wc,
        float* __restrict__ ctxW, float* __restrict__ dens_pre){
    __shared__ float ctx_l[kH];
    int b = blockIdx.x, h = threadIdx.x;
    int z = b * 256 + h;
    if (z < 5376) dens_pre[z] = 0.f;
    if (z + 4096 < 5376) dens_pre[z + 4096] = 0.f;
    float w0 = Ws[h], w1 = Ws[kH + h], bh = bs[h];
    float acc = 0.f, msum = 0.f;
    const float* e = enc_in + b * kS * 2;
    const float* mk = mask + b * kS;
    #pragma unroll 4
    for (int s = 0; s < kS; ++s){
        float e0 = e[2*s], e1 = e[2*s+1], mm = mk[s];
        float v = fmaxf(fmaf(e0, w0, fmaf(e1, w1, bh)), 0.f);
        acc = fmaf(v, mm, acc);
        msum += mm;
    }
    ctx_l[h] = acc / fmaxf(msum, 1.f);
    __syncthreads();
    float o = 0.f;
    #pragma unroll 8
    for (int k = 0; k < kH; ++k) o = fmaf(ctx_l[k], Wc[k * kH + h], o);
    ctxW[b * kH + h] = o;
}

// ---- first residual layer, fused with the input layer:
// x0 = relu(mesh @ Win + bin) computed on the fly; xout = x0 + relu(x0 @ W + b)
__global__ __launch_bounds__(256) void k_res_first(const float* __restrict__ mesh,
        const float* __restrict__ Win, const float* __restrict__ bin,
        const float* __restrict__ Wl, const float* __restrict__ bl,
        float* __restrict__ xout){
    __shared__ float xT[64 * 68];   // [k][j], padded stride 68
    __shared__ float Wsh[64 * 68];  // [k][o], padded stride 68
    __shared__ float beL[64], alL[64];
    int tid = threadIdx.x;
    int og = tid & 31, pg = tid >> 5;
    int jb = blockIdx.x * 64;
    int ob = blockIdx.y * 64;
    if (tid < 64){
        int jg = jb + tid;
        beL[tid] = (jg < kM) ? mesh[2*jg]   : 0.f;
        alL[tid] = (jg < kM) ? mesh[2*jg+1] : 0.f;
    }
    __syncthreads();
    float acc[8][2] = {};
    for (int sl = 0; sl < 4; ++sl){
        int kb = sl * 64;
        #pragma unroll
        for (int it = 0; it < 16; ++it){
            int idx = tid + it * 256;
            int k = idx & 63, j = idx >> 6;
            xT[k * 68 + j] = fmaxf(fmaf(beL[j], Win[kb + k],
                              fmaf(alL[j], Win[kH + kb + k], bin[kb + k])), 0.f);
        }
        #pragma unroll
        for (int it = 0; it < 16; ++it){
            int idx = tid + it * 256;
            int o = idx & 63, k = idx >> 6;
            Wsh[k * 68 + o] = Wl[(kb + k) * kH + ob + o];
        }
        __syncthreads();
        #pragma unroll 2
        for (int k = 0; k < 64; ++k){
            float xv[8];
            *(float4*)&xv[0] = *(const float4*)&xT[k * 68 + pg * 8];
            *(float4*)&xv[4] = *(const float4*)&xT[k * 68 + pg * 8 + 4];
            float w0 = Wsh[k * 68 + og];
            float w1 = Wsh[k * 68 + og + 32];
            #pragma unroll
            for (int i = 0; i < 8; ++i){
                acc[i][0] = fmaf(xv[i], w0, acc[i][0]);
                acc[i][1] = fmaf(xv[i], w1, acc[i][1]);
            }
        }
        __syncthreads();
    }
    #pragma unroll
    for (int i = 0; i < 8; ++i){
        int jg = jb + pg * 8 + i;
        if (jg >= kM) continue;
        float be = beL[pg * 8 + i], al = alL[pg * 8 + i];
        #pragma unroll
        for (int r = 0; r < 2; ++r){
            int o = ob + og + 32 * r;
            float x0v = fmaxf(fmaf(be, Win[o], fmaf(al, Win[kH + o], bin[o])), 0.f);
            float v = acc[i][r] + bl[o];
            xout[jg * kH + o] = x0v + fmaxf(v, 0.f);
        }
    }
}

// ---- residual layer: xout = xin + relu(xin @ W + b). Tiled fp32 GEMM.
// kDOT: also accumulate partial density logits (xout . Wout over this o-slice).
template<bool kDOT>
__global__ __launch_bounds__(256) void k_res_t(const float* __restrict__ xin,
        const float* __restrict__ Wl, const float* __restrict__ bl,
        float* __restrict__ xout, const float* __restrict__ Wout,
        float* __restrict__ dens_pre){
    __shared__ float xT[64 * 68];
    __shared__ float Wsh[64 * 68];
    int tid = threadIdx.x;
    int og = tid & 31, pg = tid >> 5;
    int jb = blockIdx.x * 64;
    int ob = blockIdx.y * 64;
    float acc[8][2] = {};
    for (int sl = 0; sl < 4; ++sl){
        int kb = sl * 64;
        #pragma unroll
        for (int it = 0; it < 16; ++it){
            int idx = tid + it * 256;
            int k = idx & 63, j = idx >> 6;
            int jg = jb + j;
            xT[k * 68 + j] = (jg < kM) ? xin[jg * kH + kb + k] : 0.f;
        }
        #pragma unroll
        for (int it = 0; it < 16; ++it){
            int idx = tid + it * 256;
            int o = idx & 63, k = idx >> 6;
            Wsh[k * 68 + o] = Wl[(kb + k) * kH + ob + o];
        }
        __syncthreads();
        #pragma unroll 2
        for (int k = 0; k < 64; ++k){
            float xv[8];
            *(float4*)&xv[0] = *(const float4*)&xT[k * 68 + pg * 8];
            *(float4*)&xv[4] = *(const float4*)&xT[k * 68 + pg * 8 + 4];
            float w0 = Wsh[k * 68 + og];
            float w1 = Wsh[k * 68 + og + 32];
            #pragma unroll
            for (int i = 0; i < 8; ++i){
                acc[i][0] = fmaf(xv[i], w0, acc[i][0]);
                acc[i][1] = fmaf(xv[i], w1, acc[i][1]);
            }
        }
        __syncthreads();
    }
    float wo0 = 0.f, wo1 = 0.f;
    if (kDOT){ wo0 = Wout[ob + og]; wo1 = Wout[ob + og + 32]; }
    #pragma unroll
    for (int i = 0; i < 8; ++i){
        int jg = jb + pg * 8 + i;
        float v0 = 0.f, v1 = 0.f;
        if (jg < kM){
            float a0 = acc[i][0] + bl[ob + og];
            float a1 = acc[i][1] + bl[ob + og + 32];
            v0 = xin[jg * kH + ob + og]      + fmaxf(a0, 0.f);
            v1 = xin[jg * kH + ob + og + 32] + fmaxf(a1, 0.f);
            xout[jg * kH + ob + og]      = v0;
            xout[jg * kH + ob + og + 32] = v1;
        }
        if (kDOT){
            float p = fmaf(v0, wo0, v1 * wo1);   // zero for invalid jg
            p += __shfl_down(p, 16, 64);
            p += __shfl_down(p, 8, 64);
            p += __shfl_down(p, 4, 64);
            p += __shfl_down(p, 2, 64);
            p += __shfl_down(p, 1, 64);
            if (og == 0 && jg < kM) atomicAdd(&dens_pre[jg], p);
        }
    }
}

// ---- scan pass 1: per (b, j, chunk) affine coefficients (A, C) over 64 t-steps.
__global__ __launch_bounds__(256) void k_scanA(const float* __restrict__ mesh,
        const float* __restrict__ dec, float* __restrict__ A, float* __restrict__ C){
    __shared__ float hsl[kL];
    int tid = threadIdx.x;
    int g = blockIdx.y, b = blockIdx.z;
    if (tid < kL) hsl[tid] = dec[b * kT + g * kL + tid] * kSig;
    __syncthreads();
    int j = blockIdx.x * 256 + tid;
    bool valid = j < kM;
    float as  = valid ? mesh[2*j+1] * kSig : 0.f;
    float bs_ = valid ? mesh[2*j]   * kSig : 0.f;
    float Aa = 1.f, Cc = 0.f;
    #pragma unroll 4
    for (int t = 0; t < kL; ++t){
        float ht = hsl[t];
        float eu = fminf(exp2_fast(as - ht), kClamp);
        float ed = fminf(exp2_fast(ht - bs_), kClamp);
        float E  = eu * ed;                       // <= 1e32, finite
        float rD = rcp_fast((1.f + eu) * (1.f + ed));
        float a  = E * rD;
        float c  = (ed - eu - 1.f) * rD;
        Aa = a * Aa;
        Cc = fmaf(a, Cc, c);
    }
    if (valid){
        int idx = (g * kB + b) * kM + j;
        A[idx] = Aa;
        C[idx] = Cc;
    }
}

// ---- density sigmoid + initial states + chunk compose (fused):
// d = sigmoid(dens_pre + bout); is = tanh(relu(mesh_feat@Wm+ctxW+bm)@Wo+bo);
// then serially compose 16 chunk-affines, writing chunk ENTRY states into A in place.
__global__ __launch_bounds__(256) void k_initB(const float* __restrict__ mesh,
        const float* __restrict__ dens_pre, const float* __restrict__ bout,
        const float* __restrict__ Wm, const float* __restrict__ bm,
        const float* __restrict__ ctxW, const float* __restrict__ Wo,
        const float* __restrict__ bo, float* __restrict__ dens,
        float* __restrict__ A, const float* __restrict__ C,
        float* __restrict__ out){
    __shared__ float w0s[kH], w1s[kH], w2s[kH], bcs[kH], wos[kH];
    int tid = threadIdx.x;
    int b = blockIdx.y;
    w0s[tid] = Wm[tid];
    w1s[tid] = Wm[kH + tid];
    w2s[tid] = Wm[2*kH + tid];
    bcs[tid] = bm[tid] + ctxW[b * kH + tid];
    wos[tid] = Wo[tid];
    __syncthreads();
    int j = blockIdx.x * 256 + tid;
    if (j >= kM) return;
    float d = 1.f / (1.f + expf(-(dens_pre[j] + bout[0])));
    if (b == 0) dens[j] = d;
    float be = mesh[2*j], al = mesh[2*j+1];
    float acc = 0.f;
    #pragma unroll 8
    for (int h = 0; h < kH; ++h){
        float pre = fmaf(be, w0s[h], fmaf(al, w1s[h], fmaf(d, w2s[h], bcs[h])));
        acc = fmaf(fmaxf(pre, 0.f), wos[h], acc);
    }
    float s = tanhf(acc + bo[0]);
    out[OFF_IS + b * kM + j] = s;
    #pragma unroll
    for (int g = 0; g < kG; ++g){
        int idx = (g * kB + b) * kM + j;
        float a = A[idx], c = C[idx];
        A[idx] = s;                 // entry state for chunk g
        s = fmaf(a, s, c);
    }
}

// ---- scan pass 2b: re-run each chunk from its entry state; bf16 LDS-transpose reduction:
// lane L ends up with the wave's 64-point partial for t = g*64+L. one bf16 store per wave.
__global__ __launch_bounds__(64) void k_scanC(const float* __restrict__ mesh,
        const float* __restrict__ dens, const float* __restrict__ sin_,
        const float* __restrict__ dec, __hip_bfloat16* __restrict__ partials,
        float* __restrict__ out){
    __shared__ __hip_bfloat16 cb[kL * 66];   // 8448 B, padded stride 66
    __shared__ float hsl[kL];
    int L = threadIdx.x;
    int jw = blockIdx.x, g = blockIdx.y, b = blockIdx.z;
    int j = jw * 64 + L;
    hsl[L] = dec[b * kT + g * kL + L] * kSig;
    bool valid = j < kM;
    float d   = valid ? dens[j] : 0.f;
    float s   = valid ? sin_[(g * kB + b) * kM + j] : 0.f;
    float be  = valid ? mesh[2*j]   : 0.f;
    float al  = valid ? mesh[2*j+1] : 0.f;
    float as  = al * kSig;
    float bs_ = be * kSig;
    if (valid && g == 0){
        // fused broadcast outputs (batch-identical density & mesh)
        out[OFF_DENS + b * kM + j] = d;
        out[OFF_MESH + 2 * (b * kM + j)]     = be;
        out[OFF_MESH + 2 * (b * kM + j) + 1] = al;
    }
    __syncthreads();
    #pragma unroll 4
    for (int t = 0; t < kL; ++t){
        float ht = hsl[t];
        float eu = fminf(exp2_fast(as - ht), kClamp);
        float ed = fminf(exp2_fast(ht - bs_), kClamp);
        float E  = eu * ed;
        float rD = rcp_fast((1.f + eu) * (1.f + ed));
        s = fmaf(E, s, ed - eu - 1.f) * rD;
        cb[t * 66 + L] = __float2bfloat16(d * s);
    }
    __syncthreads();
    float a0 = 0.f, a1 = 0.f;
    const __hip_bfloat162* row = (const __hip_bfloat162*)&cb[L * 66];
    #pragma unroll
    for (int i = 0; i < 32; ++i){
        float2 f = __bfloat1622float2(row[i]);
        a0 += f.x; a1 += f.y;
    }
    partials[(b * kJW + jw) * kT + g * kL + L] = __float2bfloat16(a0 + a1);
}

// ---- finalize: dsum reduced per-block (redundant, cheap); m = sum(partials)/dsum;
// b_out = h_scale*h + m_scale*m + m_offset
__global__ __launch_bounds__(256) void k_final(const __hip_bfloat16* __restrict__ partials,
        const float* __restrict__ dens, const float* __restrict__ dec,
        const float* __restrict__ hsr, const float* __restrict__ msr,
        const float* __restrict__ mor, float* __restrict__ out){
    __shared__ float red[4];
    int tid = threadIdx.x;
    int b = blockIdx.y;
    float ds = 0.f;
    for (int i = tid; i < kM; i += 256) ds += dens[i];
    #pragma unroll
    for (int off = 32; off; off >>= 1) ds += __shfl_down(ds, off, 64);
    if ((tid & 63) == 0) red[tid >> 6] = ds;
    __syncthreads();
    float dsum = red[0] + red[1] + red[2] + red[3];
    int t = blockIdx.x * 256 + tid;   // grid.x = 4
    float acc = 0.f;
    const __hip_bfloat16* p = partials + (long)b * kJW * kT + t;
    #pragma unroll 4
    for (int w = 0; w < kJW; ++w) acc += __bfloat162float(p[(long)w * kT]);
    float m = acc / dsum;
    float hscale = 10.f / (1.f + expf(-hsr[0]));           // [0,10]
    float mscale = 10.f / (1.f + expf(-msr[0]));           // [0,10]
    float moff   = -10.f + 20.f / (1.f + expf(-mor[0]));   // [-10,10]
    float h = dec[b * kT + t];
    out[OFF_M + b * kT + t]    = m;
    out[OFF_BOUT + b * kT + t] = fmaf(hscale, h, fmaf(mscale, m, moff));
}

extern "C" void kernel_launch(void* const* d_in, const int* in_sizes, int n_in,
                              void* d_out, int out_size, void* d_ws, size_t ws_size,
                              hipStream_t stream) {
    (void)in_sizes; (void)n_in; (void)out_size; (void)ws_size;
    const float* enc_in = (const float*)d_in[0];
    const float* dec    = (const float*)d_in[1];
    const float* mask   = (const float*)d_in[2];
    const float* mesh   = (const float*)d_in[3];
    const float* Win    = (const float*)d_in[4];
    const float* bin    = (const float*)d_in[5];
    const float* Wr     = (const float*)d_in[6];
    const float* br     = (const float*)d_in[7];
    const float* Wout   = (const float*)d_in[8];
    const float* bout   = (const float*)d_in[9];
    const float* Ws     = (const float*)d_in[10];
    const float* bs     = (const float*)d_in[11];
    const float* Wm     = (const float*)d_in[12];
    const float* Wc     = (const float*)d_in[13];
    const float* bm     = (const float*)d_in[14];
    const float* Wo     = (const float*)d_in[15];
    const float* bo     = (const float*)d_in[16];
    const float* hsr    = (const float*)d_in[17];
    const float* msr    = (const float*)d_in[18];
    const float* mor    = (const float*)d_in[19];
    float* out = (float*)d_out;

    float* ws    = (float*)d_ws;
    float* S1    = ws + WS_S1;     // x1/x3 -> A -> entry states
    float* S2    = ws + WS_S2;     // x2 -> C -> partials(bf16)
    float* densv = ws + WS_DENS;
    float* densp = ws + WS_DENSP;
    float* ctxW  = ws + WS_CTXW;
    __hip_bfloat16* partials = (__hip_bfloat16*)S2;

    k_enc         <<<dim3(kB),         256, 0, stream>>>(enc_in, mask, Ws, bs, Wc, ctxW, densp);
    k_res_first   <<<dim3(81, 4),      256, 0, stream>>>(mesh, Win, bin, Wr, br, S1);
    k_res_t<false><<<dim3(81, 4),      256, 0, stream>>>(S1, Wr + 65536,  br + 256, S2, nullptr, nullptr);
    k_res_t<true> <<<dim3(81, 4),      256, 0, stream>>>(S2, Wr + 131072, br + 512, S1, Wout, densp);
    k_scanA       <<<dim3(21, kG, kB), 256, 0, stream>>>(mesh, dec, S1 + 0, S2);   // wait: S1 holds x3!
    // NOTE: scanA writes A into S1 — but S1 still holds x3 which k_initB no longer needs
    // (density logits already accumulated into densp by k_res_t<true>). Safe.
    k_initB       <<<dim3(21, kB),     256, 0, stream>>>(mesh, densp, bout, Wm, bm, ctxW, Wo, bo, densv, S1, S2, out);
    k_scanC       <<<dim3(kJW, kG, kB), 64, 0, stream>>>(mesh, densv, S1, dec, partials, out);
    k_final       <<<dim3(4, kB),      256, 0, stream>>>(partials, densv, dec, hsr, msr, mor, out);
}

// Round 8
// 319.303 us; speedup vs baseline: 1.9093x; 1.1118x over previous
//
#include <hip/hip_runtime.h>
#include <hip/hip_bf16.h>
#include <math.h>

constexpr int kB = 16;
constexpr int kS = 256;
constexpr int kT = 1024;
constexpr int kM = 5151;
constexpr int kH = 256;
constexpr int kG = 16;                   // t-chunks
constexpr int kL = 64;                   // t's per chunk
constexpr int kJW = 84;                  // ceil(M/64) j-waves
constexpr float kSig = 1442.6950408889634f; // 1000 * log2(e)
constexpr float kAiS = 14.426950408889634f; // kSig / 100 (per alpha-index)
constexpr float kClamp = 1e16f;          // exp clamp: products stay < fp32 max (1e32)

constexpr int OFF_BOUT = 0;
constexpr int OFF_DENS = kB * kT;                 // 16384
constexpr int OFF_M    = OFF_DENS + kB * kM;      // 98800
constexpr int OFF_IS   = OFF_M + kB * kT;         // 115184
constexpr int OFF_MESH = OFF_IS + kB * kM;        // 197600

// workspace layout (float-slot offsets). Proven ws >= 2729728 floats (R3 run).
// lifetimes: x1 [res_first..res2] ; x2 [res2..res3] ; TAB [k_tab..scanC] (aliases x1)
// A(bf16) [scanA..scanC as entry-q] ; C(bf16) [scanA..initB] ; partials(bf16) aliases C.
constexpr int WS_X1   = 0;        // 1318656 fp32
constexpr int WS_X2   = 1318656;  // 1318656 fp32
constexpr int WS_TAB  = 0;        // 1654784 bf16 = 827392 slots (over dead x1)
constexpr int WS_A    = 827392;   // 1318656 bf16 = 659328 slots (ends 1486720)
constexpr int WS_C    = 1486720;  // 1318656 bf16 = 659328 slots (ends 2146048)
constexpr int WS_PART = 1486720;  // 1376256 bf16 = 688128 slots (aliases dead C)
constexpr int WS_DENS = 2637312;  // 5376
constexpr int WS_DENSP= 2642688;  // 5376
constexpr int WS_CTXW = 2648064;  // 4096 (end 2652160 < 2729728 ok)

__device__ __forceinline__ float exp2_fast(float x){ return __builtin_amdgcn_exp2f(x); }
__device__ __forceinline__ float rcp_fast(float x){ return __builtin_amdgcn_rcpf(x); }

// ---- encoder context: ctx = masked-mean(relu(enc_in @ Ws + bs)); ctxW = ctx @ Wc
// also zeroes dens_pre (stream-ordered before any accumulation).
__global__ __launch_bounds__(256) void k_enc(const float* __restrict__ enc_in,
        const float* __restrict__ mask, const float* __restrict__ Ws,
        const float* __restrict__ bs, const float* __restrict__ Wc,
        float* __restrict__ ctxW, float* __restrict__ dens_pre){
    __shared__ float ctx_l[kH];
    int b = blockIdx.x, h = threadIdx.x;
    int z = b * 256 + h;
    if (z < 5376) dens_pre[z] = 0.f;
    if (z + 4096 < 5376) dens_pre[z + 4096] = 0.f;
    float w0 = Ws[h], w1 = Ws[kH + h], bh = bs[h];
    float acc = 0.f, msum = 0.f;
    const float* e = enc_in + b * kS * 2;
    const float* mk = mask + b * kS;
    #pragma unroll 4
    for (int s = 0; s < kS; ++s){
        float e0 = e[2*s], e1 = e[2*s+1], mm = mk[s];
        float v = fmaxf(fmaf(e0, w0, fmaf(e1, w1, bh)), 0.f);
        acc = fmaf(v, mm, acc);
        msum += mm;
    }
    ctx_l[h] = acc / fmaxf(msum, 1.f);
    __syncthreads();
    float o = 0.f;
    #pragma unroll 8
    for (int k = 0; k < kH; ++k) o = fmaf(ctx_l[k], Wc[k * kH + h], o);
    ctxW[b * kH + h] = o;
}

// ---- first residual layer, fused with the input layer.
__global__ __launch_bounds__(256) void k_res_first(const float* __restrict__ mesh,
        const float* __restrict__ Win, const float* __restrict__ bin,
        const float* __restrict__ Wl, const float* __restrict__ bl,
        float* __restrict__ xout){
    __shared__ float xT[64 * 68];
    __shared__ float Wsh[64 * 68];
    __shared__ float beL[64], alL[64];
    int tid = threadIdx.x;
    int og = tid & 31, pg = tid >> 5;
    int jb = blockIdx.x * 64;
    int ob = blockIdx.y * 64;
    if (tid < 64){
        int jg = jb + tid;
        beL[tid] = (jg < kM) ? mesh[2*jg]   : 0.f;
        alL[tid] = (jg < kM) ? mesh[2*jg+1] : 0.f;
    }
    __syncthreads();
    float acc[8][2] = {};
    for (int sl = 0; sl < 4; ++sl){
        int kb = sl * 64;
        #pragma unroll
        for (int it = 0; it < 16; ++it){
            int idx = tid + it * 256;
            int k = idx & 63, j = idx >> 6;
            xT[k * 68 + j] = fmaxf(fmaf(beL[j], Win[kb + k],
                              fmaf(alL[j], Win[kH + kb + k], bin[kb + k])), 0.f);
        }
        #pragma unroll
        for (int it = 0; it < 16; ++it){
            int idx = tid + it * 256;
            int o = idx & 63, k = idx >> 6;
            Wsh[k * 68 + o] = Wl[(kb + k) * kH + ob + o];
        }
        __syncthreads();
        #pragma unroll 2
        for (int k = 0; k < 64; ++k){
            float xv[8];
            *(float4*)&xv[0] = *(const float4*)&xT[k * 68 + pg * 8];
            *(float4*)&xv[4] = *(const float4*)&xT[k * 68 + pg * 8 + 4];
            float w0 = Wsh[k * 68 + og];
            float w1 = Wsh[k * 68 + og + 32];
            #pragma unroll
            for (int i = 0; i < 8; ++i){
                acc[i][0] = fmaf(xv[i], w0, acc[i][0]);
                acc[i][1] = fmaf(xv[i], w1, acc[i][1]);
            }
        }
        __syncthreads();
    }
    #pragma unroll
    for (int i = 0; i < 8; ++i){
        int jg = jb + pg * 8 + i;
        if (jg >= kM) continue;
        float be = beL[pg * 8 + i], al = alL[pg * 8 + i];
        #pragma unroll
        for (int r = 0; r < 2; ++r){
            int o = ob + og + 32 * r;
            float x0v = fmaxf(fmaf(be, Win[o], fmaf(al, Win[kH + o], bin[o])), 0.f);
            float v = acc[i][r] + bl[o];
            xout[jg * kH + o] = x0v + fmaxf(v, 0.f);
        }
    }
}

// ---- residual layer: kDOT=false: xout = xin + relu(xin @ W + b).
// kDOT=true: no xout write; accumulate density logits (x3 . Wout slice) into dens_pre.
template<bool kDOT>
__global__ __launch_bounds__(256) void k_res_t(const float* __restrict__ xin,
        const float* __restrict__ Wl, const float* __restrict__ bl,
        float* __restrict__ xout, const float* __restrict__ Wout,
        float* __restrict__ dens_pre){
    __shared__ float xT[64 * 68];
    __shared__ float Wsh[64 * 68];
    int tid = threadIdx.x;
    int og = tid & 31, pg = tid >> 5;
    int jb = blockIdx.x * 64;
    int ob = blockIdx.y * 64;
    float acc[8][2] = {};
    for (int sl = 0; sl < 4; ++sl){
        int kb = sl * 64;
        #pragma unroll
        for (int it = 0; it < 16; ++it){
            int idx = tid + it * 256;
            int k = idx & 63, j = idx >> 6;
            int jg = jb + j;
            xT[k * 68 + j] = (jg < kM) ? xin[jg * kH + kb + k] : 0.f;
        }
        #pragma unroll
        for (int it = 0; it < 16; ++it){
            int idx = tid + it * 256;
            int o = idx & 63, k = idx >> 6;
            Wsh[k * 68 + o] = Wl[(kb + k) * kH + ob + o];
        }
        __syncthreads();
        #pragma unroll 2
        for (int k = 0; k < 64; ++k){
            float xv[8];
            *(float4*)&xv[0] = *(const float4*)&xT[k * 68 + pg * 8];
            *(float4*)&xv[4] = *(const float4*)&xT[k * 68 + pg * 8 + 4];
            float w0 = Wsh[k * 68 + og];
            float w1 = Wsh[k * 68 + og + 32];
            #pragma unroll
            for (int i = 0; i < 8; ++i){
                acc[i][0] = fmaf(xv[i], w0, acc[i][0]);
                acc[i][1] = fmaf(xv[i], w1, acc[i][1]);
            }
        }
        __syncthreads();
    }
    float wo0 = 0.f, wo1 = 0.f;
    if (kDOT){ wo0 = Wout[ob + og]; wo1 = Wout[ob + og + 32]; }
    #pragma unroll
    for (int i = 0; i < 8; ++i){
        int jg = jb + pg * 8 + i;
        float v0 = 0.f, v1 = 0.f;
        if (jg < kM){
            float a0 = acc[i][0] + bl[ob + og];
            float a1 = acc[i][1] + bl[ob + og + 32];
            v0 = xin[jg * kH + ob + og]      + fmaxf(a0, 0.f);
            v1 = xin[jg * kH + ob + og + 32] + fmaxf(a1, 0.f);
            if (!kDOT){
                xout[jg * kH + ob + og]      = v0;
                xout[jg * kH + ob + og + 32] = v1;
            }
        }
        if (kDOT){
            float p = fmaf(v0, wo0, v1 * wo1);   // zero for invalid jg
            p += __shfl_down(p, 16, 64);
            p += __shfl_down(p, 8, 64);
            p += __shfl_down(p, 4, 64);
            p += __shfl_down(p, 2, 64);
            p += __shfl_down(p, 1, 64);
            if (og == 0 && jg < kM) atomicAdd(&dens_pre[jg], p);
        }
    }
}

// ---- sigmoid-exponential table: TAB[b][ai][t] = min(exp2(ai*kAiS - h[b][t]*kSig), 1e16)
// eu(alpha_j) = TAB[b][ai_j][t]; ed(beta_j) = 1/TAB[b][bi_j][t] (exact identity).
__global__ __launch_bounds__(256) void k_tab(const float* __restrict__ dec,
        __hip_bfloat16* __restrict__ TAB){
    int t  = blockIdx.x * 256 + threadIdx.x;   // grid.x = 4
    int ai = blockIdx.y;                        // 101
    int b  = blockIdx.z;                        // 16
    float hts = dec[b * kT + t] * kSig;
    float v = fminf(exp2_fast(fmaf((float)ai, kAiS, -hts)), kClamp);
    TAB[(size_t)(b * 101 + ai) * kT + t] = __float2bfloat16(v);
}

__device__ __forceinline__ float bfhalf(unsigned int w, int odd){
    return __uint_as_float(odd ? (w & 0xffff0000u) : (w << 16));
}

// ---- scan pass 1: per (b, j, chunk) q-affine (A, C) over 64 t-steps.
// q-step (q = s+1): q' = (ea*q + 2) / ((1+ea)(1+eb))  [exact rewrite, 1 rcp, 0 exp2]
__global__ __launch_bounds__(256) void k_scanA(const float* __restrict__ mesh,
        const __hip_bfloat16* __restrict__ TAB,
        __hip_bfloat16* __restrict__ A, __hip_bfloat16* __restrict__ C){
    int tid = threadIdx.x;
    int g = blockIdx.y, b = blockIdx.z;
    int j = blockIdx.x * 256 + tid;
    bool valid = j < kM;
    int jj = valid ? j : 0;
    int ai = __float2int_rn(mesh[2*jj+1] * 100.f);
    int bi = __float2int_rn(mesh[2*jj]   * 100.f);
    const __hip_bfloat16* base = TAB + (size_t)b * 101 * kT + g * kL;
    const uint4* pa = (const uint4*)(base + (size_t)ai * kT);
    const uint4* pb = (const uint4*)(base + (size_t)bi * kT);
    unsigned int ua[32], ub[32];
    #pragma unroll
    for (int i = 0; i < 8; ++i){
        uint4 va = pa[i]; uint4 vb = pb[i];
        ua[4*i]=va.x; ua[4*i+1]=va.y; ua[4*i+2]=va.z; ua[4*i+3]=va.w;
        ub[4*i]=vb.x; ub[4*i+1]=vb.y; ub[4*i+2]=vb.z; ub[4*i+3]=vb.w;
    }
    float Aa = 1.f, Cc = 0.f;   // q_out = Aa*q_in + Cc
    #pragma unroll
    for (int t = 0; t < kL; ++t){
        float ea = bfhalf(ua[t>>1], t & 1);
        float eb = bfhalf(ub[t>>1], t & 1);
        float rD = rcp_fast((1.f + ea) * (1.f + eb));
        float aq = ea * rD;
        Aa = aq * Aa;
        Cc = fmaf(aq, Cc, rD + rD);
    }
    if (valid){
        size_t idx = (size_t)(g * kB + b) * kM + j;
        A[idx] = __float2bfloat16(Aa);
        C[idx] = __float2bfloat16(Cc);
    }
}

// ---- density sigmoid + initial states + chunk compose (fused, q-space):
__global__ __launch_bounds__(256) void k_initB(const float* __restrict__ mesh,
        const float* __restrict__ dens_pre, const float* __restrict__ bout,
        const float* __restrict__ Wm, const float* __restrict__ bm,
        const float* __restrict__ ctxW, const float* __restrict__ Wo,
        const float* __restrict__ bo, float* __restrict__ dens,
        __hip_bfloat16* __restrict__ A, const __hip_bfloat16* __restrict__ C,
        float* __restrict__ out){
    __shared__ float w0s[kH], w1s[kH], w2s[kH], bcs[kH], wos[kH];
    int tid = threadIdx.x;
    int b = blockIdx.y;
    w0s[tid] = Wm[tid];
    w1s[tid] = Wm[kH + tid];
    w2s[tid] = Wm[2*kH + tid];
    bcs[tid] = bm[tid] + ctxW[b * kH + tid];
    wos[tid] = Wo[tid];
    __syncthreads();
    int j = blockIdx.x * 256 + tid;
    if (j >= kM) return;
    float d = 1.f / (1.f + expf(-(dens_pre[j] + bout[0])));
    if (b == 0) dens[j] = d;
    float be = mesh[2*j], al = mesh[2*j+1];
    float acc = 0.f;
    #pragma unroll 8
    for (int h = 0; h < kH; ++h){
        float pre = fmaf(be, w0s[h], fmaf(al, w1s[h], fmaf(d, w2s[h], bcs[h])));
        acc = fmaf(fmaxf(pre, 0.f), wos[h], acc);
    }
    float s = tanhf(acc + bo[0]);
    out[OFF_IS + b * kM + j] = s;
    float q = s + 1.f;
    #pragma unroll
    for (int g = 0; g < kG; ++g){
        size_t idx = (size_t)(g * kB + b) * kM + j;
        float a = __bfloat162float(A[idx]), c = __bfloat162float(C[idx]);
        A[idx] = __float2bfloat16(q);       // entry q for chunk g
        q = fmaf(a, q, c);
    }
}

// ---- scan pass 2: replay each chunk from entry q; bf16 LDS-transpose reduction.
__global__ __launch_bounds__(64) void k_scanC(const float* __restrict__ mesh,
        const float* __restrict__ dens, const __hip_bfloat16* __restrict__ qin,
        const __hip_bfloat16* __restrict__ TAB,
        __hip_bfloat16* __restrict__ partials, float* __restrict__ out){
    __shared__ __hip_bfloat16 cb[kL * 66];
    int L = threadIdx.x;
    int jw = blockIdx.x, g = blockIdx.y, b = blockIdx.z;
    int j = jw * 64 + L;
    bool valid = j < kM;
    int jj = valid ? j : 0;
    float d  = valid ? dens[j] : 0.f;
    float q  = valid ? __bfloat162float(qin[(size_t)(g * kB + b) * kM + j]) : 0.f;
    float be = mesh[2*jj], al = mesh[2*jj+1];
    int ai = __float2int_rn(al * 100.f);
    int bi = __float2int_rn(be * 100.f);
    const __hip_bfloat16* base = TAB + (size_t)b * 101 * kT + g * kL;
    const uint4* pa = (const uint4*)(base + (size_t)ai * kT);
    const uint4* pb = (const uint4*)(base + (size_t)bi * kT);
    unsigned int ua[32], ub[32];
    #pragma unroll
    for (int i = 0; i < 8; ++i){
        uint4 va = pa[i]; uint4 vb = pb[i];
        ua[4*i]=va.x; ua[4*i+1]=va.y; ua[4*i+2]=va.z; ua[4*i+3]=va.w;
        ub[4*i]=vb.x; ub[4*i+1]=vb.y; ub[4*i+2]=vb.z; ub[4*i+3]=vb.w;
    }
    if (valid && g == 0){
        out[OFF_DENS + b * kM + j] = d;
        out[OFF_MESH + 2 * (b * kM + j)]     = be;
        out[OFF_MESH + 2 * (b * kM + j) + 1] = al;
    }
    #pragma unroll
    for (int t = 0; t < kL; ++t){
        float ea = bfhalf(ua[t>>1], t & 1);
        float eb = bfhalf(ub[t>>1], t & 1);
        float rD = rcp_fast((1.f + ea) * (1.f + eb));
        q = fmaf(ea, q, 2.f) * rD;
        cb[t * 66 + L] = __float2bfloat16(fmaf(d, q, -d));   // d*s = d*q - d
    }
    __syncthreads();
    float a0 = 0.f, a1 = 0.f;
    const __hip_bfloat162* row = (const __hip_bfloat162*)&cb[L * 66];
    #pragma unroll
    for (int i = 0; i < 32; ++i){
        float2 f = __bfloat1622float2(row[i]);
        a0 += f.x; a1 += f.y;
    }
    partials[(size_t)(b * kJW + jw) * kT + g * kL + L] = __float2bfloat16(a0 + a1);
}

// ---- finalize: per-block dsum; m = sum(partials)/dsum; b_out = hs*h + ms*m + mo
__global__ __launch_bounds__(256) void k_final(const __hip_bfloat16* __restrict__ partials,
        const float* __restrict__ dens, const float* __restrict__ dec,
        const float* __restrict__ hsr, const float* __restrict__ msr,
        const float* __restrict__ mor, float* __restrict__ out){
    __shared__ float red[4];
    int tid = threadIdx.x;
    int b = blockIdx.y;
    float ds = 0.f;
    for (int i = tid; i < kM; i += 256) ds += dens[i];
    #pragma unroll
    for (int off = 32; off; off >>= 1) ds += __shfl_down(ds, off, 64);
    if ((tid & 63) == 0) red[tid >> 6] = ds;
    __syncthreads();
    float dsum = red[0] + red[1] + red[2] + red[3];
    int t = blockIdx.x * 256 + tid;   // grid.x = 4
    float acc = 0.f;
    const __hip_bfloat16* p = partials + (size_t)b * kJW * kT + t;
    #pragma unroll 4
    for (int w = 0; w < kJW; ++w) acc += __bfloat162float(p[(size_t)w * kT]);
    float m = acc / dsum;
    float hscale = 10.f / (1.f + expf(-hsr[0]));
    float mscale = 10.f / (1.f + expf(-msr[0]));
    float moff   = -10.f + 20.f / (1.f + expf(-mor[0]));
    float h = dec[b * kT + t];
    out[OFF_M + b * kT + t]    = m;
    out[OFF_BOUT + b * kT + t] = fmaf(hscale, h, fmaf(mscale, m, moff));
}

extern "C" void kernel_launch(void* const* d_in, const int* in_sizes, int n_in,
                              void* d_out, int out_size, void* d_ws, size_t ws_size,
                              hipStream_t stream) {
    (void)in_sizes; (void)n_in; (void)out_size; (void)ws_size;
    const float* enc_in = (const float*)d_in[0];
    const float* dec    = (const float*)d_in[1];
    const float* mask   = (const float*)d_in[2];
    const float* mesh   = (const float*)d_in[3];
    const float* Win    = (const float*)d_in[4];
    const float* bin    = (const float*)d_in[5];
    const float* Wr     = (const float*)d_in[6];
    const float* br     = (const float*)d_in[7];
    const float* Wout   = (const float*)d_in[8];
    const float* bout   = (const float*)d_in[9];
    const float* Ws     = (const float*)d_in[10];
    const float* bs     = (const float*)d_in[11];
    const float* Wm     = (const float*)d_in[12];
    const float* Wc     = (const float*)d_in[13];
    const float* bm     = (const float*)d_in[14];
    const float* Wo     = (const float*)d_in[15];
    const float* bo     = (const float*)d_in[16];
    const float* hsr    = (const float*)d_in[17];
    const float* msr    = (const float*)d_in[18];
    const float* mor    = (const float*)d_in[19];
    float* out = (float*)d_out;

    float* ws = (float*)d_ws;
    float* x1    = ws + WS_X1;
    float* x2    = ws + WS_X2;
    float* densv = ws + WS_DENS;
    float* densp = ws + WS_DENSP;
    float* ctxW  = ws + WS_CTXW;
    __hip_bfloat16* TAB      = (__hip_bfloat16*)(ws + WS_TAB);
    __hip_bfloat16* A        = (__hip_bfloat16*)(ws + WS_A);
    __hip_bfloat16* C        = (__hip_bfloat16*)(ws + WS_C);
    __hip_bfloat16* partials = (__hip_bfloat16*)(ws + WS_PART);

    k_enc         <<<dim3(kB),          256, 0, stream>>>(enc_in, mask, Ws, bs, Wc, ctxW, densp);
    k_res_first   <<<dim3(81, 4),       256, 0, stream>>>(mesh, Win, bin, Wr, br, x1);
    k_res_t<false><<<dim3(81, 4),       256, 0, stream>>>(x1, Wr + 65536,  br + 256, x2, nullptr, nullptr);
    k_res_t<true> <<<dim3(81, 4),       256, 0, stream>>>(x2, Wr + 131072, br + 512, nullptr, Wout, densp);
    k_tab         <<<dim3(4, 101, kB),  256, 0, stream>>>(dec, TAB);   // x1 dead -> TAB aliases it
    k_scanA       <<<dim3(21, kG, kB),  256, 0, stream>>>(mesh, TAB, A, C);
    k_initB       <<<dim3(21, kB),      256, 0, stream>>>(mesh, densp, bout, Wm, bm, ctxW, Wo, bo, densv, A, C, out);
    k_scanC       <<<dim3(kJW, kG, kB),  64, 0, stream>>>(mesh, densv, A, TAB, partials, out);
    k_final       <<<dim3(4, kB),       256, 0, stream>>>(partials, densv, dec, hsr, msr, mor, out);
}

// Round 9
// 283.199 us; speedup vs baseline: 2.1527x; 1.1275x over previous
//
#include <hip/hip_runtime.h>
#include <hip/hip_bf16.h>
#include <math.h>

constexpr int kB = 16;
constexpr int kS = 256;
constexpr int kT = 1024;
constexpr int kM = 5151;
constexpr int kH = 256;
constexpr int kG = 16;                   // t-chunks
constexpr int kL = 64;                   // t's per chunk
constexpr int kJW = 84;                  // ceil(M/64) j-waves
constexpr float kSig = 1442.6950408889634f; // 1000 * log2(e)
constexpr float kAiS = 14.426950408889634f; // kSig / 100 (per alpha-index)
constexpr float kClamp = 1e16f;          // exp clamp: products stay < fp32 max (1e32)

constexpr int OFF_BOUT = 0;
constexpr int OFF_DENS = kB * kT;                 // 16384
constexpr int OFF_M    = OFF_DENS + kB * kM;      // 98800
constexpr int OFF_IS   = OFF_M + kB * kT;         // 115184
constexpr int OFF_MESH = OFF_IS + kB * kM;        // 197600

// workspace layout (float-slot offsets). Proven ws >= 2729728 floats (R3 run).
constexpr int WS_X1   = 0;        // 1318656 fp32
constexpr int WS_X2   = 1318656;  // 1318656 fp32
constexpr int WS_TAB  = 0;        // 1654784 bf16 = 827392 slots (over dead x1)
constexpr int WS_A    = 827392;   // bf16, ends 1486720
constexpr int WS_C    = 1486720;  // bf16, ends 2146048
constexpr int WS_PART = 1486720;  // bf16 partials alias dead C
constexpr int WS_DENS = 2637312;  // 5376
constexpr int WS_DENSP= 2642688;  // 5376
constexpr int WS_CTXW = 2648064;  // 4096 (end 2652160 < 2729728 ok)

__device__ __forceinline__ float exp2_fast(float x){ return __builtin_amdgcn_exp2f(x); }
__device__ __forceinline__ float rcp_fast(float x){ return __builtin_amdgcn_rcpf(x); }

// ---- encoder context: ctx = masked-mean(relu(enc_in @ Ws + bs)); ctxW = ctx @ Wc
__global__ __launch_bounds__(256) void k_enc(const float* __restrict__ enc_in,
        const float* __restrict__ mask, const float* __restrict__ Ws,
        const float* __restrict__ bs, const float* __restrict__ Wc,
        float* __restrict__ ctxW, float* __restrict__ dens_pre){
    __shared__ float ctx_l[kH];
    int b = blockIdx.x, h = threadIdx.x;
    int z = b * 256 + h;
    if (z < 5376) dens_pre[z] = 0.f;
    if (z + 4096 < 5376) dens_pre[z + 4096] = 0.f;
    float w0 = Ws[h], w1 = Ws[kH + h], bh = bs[h];
    float acc = 0.f, msum = 0.f;
    const float* e = enc_in + b * kS * 2;
    const float* mk = mask + b * kS;
    #pragma unroll 4
    for (int s = 0; s < kS; ++s){
        float e0 = e[2*s], e1 = e[2*s+1], mm = mk[s];
        float v = fmaxf(fmaf(e0, w0, fmaf(e1, w1, bh)), 0.f);
        acc = fmaf(v, mm, acc);
        msum += mm;
    }
    ctx_l[h] = acc / fmaxf(msum, 1.f);
    __syncthreads();
    float o = 0.f;
    #pragma unroll 8
    for (int k = 0; k < kH; ++k) o = fmaf(ctx_l[k], Wc[k * kH + h], o);
    ctxW[b * kH + h] = o;
}

// ---- first residual layer fused with input layer. 32j x 64o tile, grid 161x4.
__global__ __launch_bounds__(256) void k_res_first(const float* __restrict__ mesh,
        const float* __restrict__ Win, const float* __restrict__ bin,
        const float* __restrict__ Wl, const float* __restrict__ bl,
        float* __restrict__ xout){
    __shared__ float xT[64 * 34];   // [k][j], stride 34 (8B-aligned float2 reads)
    __shared__ float Wsh[64 * 64];  // [k][o], conflict-free both directions
    __shared__ float beL[32], alL[32];
    int tid = threadIdx.x;
    int og = tid & 31, pg = tid >> 5;       // 2 outs, 4 points per thread
    int jb = blockIdx.x * 32;
    int ob = blockIdx.y * 64;
    if (tid < 32){
        int jg = jb + tid;
        beL[tid] = (jg < kM) ? mesh[2*jg]   : 0.f;
        alL[tid] = (jg < kM) ? mesh[2*jg+1] : 0.f;
    }
    __syncthreads();
    float acc[4][2] = {};
    int ks = tid & 63;    // staging k: constant per thread
    int j0 = tid >> 6;    // staging j base: 0..3
    for (int sl = 0; sl < 4; ++sl){
        int kb = sl * 64;
        float w0k = Win[kb + ks], w1k = Win[kH + kb + ks], bk = bin[kb + ks];
        #pragma unroll
        for (int it = 0; it < 8; ++it){
            int j = j0 + it * 4;
            xT[ks * 34 + j] = fmaxf(fmaf(beL[j], w0k, fmaf(alL[j], w1k, bk)), 0.f);
        }
        #pragma unroll
        for (int it = 0; it < 16; ++it){
            int idx = tid + it * 256;
            int o = idx & 63, k = idx >> 6;
            Wsh[k * 64 + o] = Wl[(kb + k) * kH + ob + o];
        }
        __syncthreads();
        #pragma unroll 4
        for (int k = 0; k < 64; ++k){
            float2 x01 = *(const float2*)&xT[k * 34 + pg * 4];
            float2 x23 = *(const float2*)&xT[k * 34 + pg * 4 + 2];
            float w0 = Wsh[k * 64 + og];
            float w1 = Wsh[k * 64 + og + 32];
            acc[0][0] = fmaf(x01.x, w0, acc[0][0]); acc[0][1] = fmaf(x01.x, w1, acc[0][1]);
            acc[1][0] = fmaf(x01.y, w0, acc[1][0]); acc[1][1] = fmaf(x01.y, w1, acc[1][1]);
            acc[2][0] = fmaf(x23.x, w0, acc[2][0]); acc[2][1] = fmaf(x23.x, w1, acc[2][1]);
            acc[3][0] = fmaf(x23.y, w0, acc[3][0]); acc[3][1] = fmaf(x23.y, w1, acc[3][1]);
        }
        __syncthreads();
    }
    #pragma unroll
    for (int i = 0; i < 4; ++i){
        int jl = pg * 4 + i;
        int jg = jb + jl;
        if (jg >= kM) continue;
        float be = beL[jl], al = alL[jl];
        #pragma unroll
        for (int r = 0; r < 2; ++r){
            int o = ob + og + 32 * r;
            float x0v = fmaxf(fmaf(be, Win[o], fmaf(al, Win[kH + o], bin[o])), 0.f);
            float v = acc[i][r] + bl[o];
            xout[jg * kH + o] = x0v + fmaxf(v, 0.f);
        }
    }
}

// ---- residual layer, 32j x 64o tile. kDOT=false: xout = xin + relu(xin@W+b).
// kDOT=true: no xout; accumulate density logits (x3 . Wout slice) into dens_pre.
template<bool kDOT>
__global__ __launch_bounds__(256) void k_res_t(const float* __restrict__ xin,
        const float* __restrict__ Wl, const float* __restrict__ bl,
        float* __restrict__ xout, const float* __restrict__ Wout,
        float* __restrict__ dens_pre){
    __shared__ float xT[64 * 34];
    __shared__ float Wsh[64 * 64];
    int tid = threadIdx.x;
    int og = tid & 31, pg = tid >> 5;
    int jb = blockIdx.x * 32;
    int ob = blockIdx.y * 64;
    float acc[4][2] = {};
    int ks = tid & 63;
    int j0 = tid >> 6;
    for (int sl = 0; sl < 4; ++sl){
        int kb = sl * 64;
        #pragma unroll
        for (int it = 0; it < 8; ++it){
            int j = j0 + it * 4;
            int jg = jb + j;
            xT[ks * 34 + j] = (jg < kM) ? xin[jg * kH + kb + ks] : 0.f;
        }
        #pragma unroll
        for (int it = 0; it < 16; ++it){
            int idx = tid + it * 256;
            int o = idx & 63, k = idx >> 6;
            Wsh[k * 64 + o] = Wl[(kb + k) * kH + ob + o];
        }
        __syncthreads();
        #pragma unroll 4
        for (int k = 0; k < 64; ++k){
            float2 x01 = *(const float2*)&xT[k * 34 + pg * 4];
            float2 x23 = *(const float2*)&xT[k * 34 + pg * 4 + 2];
            float w0 = Wsh[k * 64 + og];
            float w1 = Wsh[k * 64 + og + 32];
            acc[0][0] = fmaf(x01.x, w0, acc[0][0]); acc[0][1] = fmaf(x01.x, w1, acc[0][1]);
            acc[1][0] = fmaf(x01.y, w0, acc[1][0]); acc[1][1] = fmaf(x01.y, w1, acc[1][1]);
            acc[2][0] = fmaf(x23.x, w0, acc[2][0]); acc[2][1] = fmaf(x23.x, w1, acc[2][1]);
            acc[3][0] = fmaf(x23.y, w0, acc[3][0]); acc[3][1] = fmaf(x23.y, w1, acc[3][1]);
        }
        __syncthreads();
    }
    float wo0 = 0.f, wo1 = 0.f;
    if (kDOT){ wo0 = Wout[ob + og]; wo1 = Wout[ob + og + 32]; }
    #pragma unroll
    for (int i = 0; i < 4; ++i){
        int jg = jb + pg * 4 + i;
        float v0 = 0.f, v1 = 0.f;
        if (jg < kM){
            float a0 = acc[i][0] + bl[ob + og];
            float a1 = acc[i][1] + bl[ob + og + 32];
            v0 = xin[jg * kH + ob + og]      + fmaxf(a0, 0.f);
            v1 = xin[jg * kH + ob + og + 32] + fmaxf(a1, 0.f);
            if (!kDOT){
                xout[jg * kH + ob + og]      = v0;
                xout[jg * kH + ob + og + 32] = v1;
            }
        }
        if (kDOT){
            float p = fmaf(v0, wo0, v1 * wo1);   // zero for invalid jg
            p += __shfl_down(p, 16, 64);
            p += __shfl_down(p, 8, 64);
            p += __shfl_down(p, 4, 64);
            p += __shfl_down(p, 2, 64);
            p += __shfl_down(p, 1, 64);
            if (og == 0 && jg < kM) atomicAdd(&dens_pre[jg], p);
        }
    }
}

// ---- sigmoid-exponential table: TAB[b][ai][t] = min(exp2(ai*kAiS - h[b][t]*kSig), 1e16)
__global__ __launch_bounds__(256) void k_tab(const float* __restrict__ dec,
        __hip_bfloat16* __restrict__ TAB){
    int t  = blockIdx.x * 256 + threadIdx.x;   // grid.x = 4
    int ai = blockIdx.y;                        // 101
    int b  = blockIdx.z;                        // 16
    float hts = dec[b * kT + t] * kSig;
    float v = fminf(exp2_fast(fmaf((float)ai, kAiS, -hts)), kClamp);
    TAB[(size_t)(b * 101 + ai) * kT + t] = __float2bfloat16(v);
}

__device__ __forceinline__ float bfhalf(unsigned int w, int odd){
    return __uint_as_float(odd ? (w & 0xffff0000u) : (w << 16));
}

// ---- scan pass 1: per (b, j, chunk) q-affine (A, C) over 64 t-steps.
// q-step (q = s+1): q' = (ea*q + 2) / ((1+ea)(1+eb))
__global__ __launch_bounds__(256) void k_scanA(const float* __restrict__ mesh,
        const __hip_bfloat16* __restrict__ TAB,
        __hip_bfloat16* __restrict__ A, __hip_bfloat16* __restrict__ C){
    int tid = threadIdx.x;
    int g = blockIdx.y, b = blockIdx.z;
    int j = blockIdx.x * 256 + tid;
    bool valid = j < kM;
    int jj = valid ? j : 0;
    int ai = __float2int_rn(mesh[2*jj+1] * 100.f);
    int bi = __float2int_rn(mesh[2*jj]   * 100.f);
    const __hip_bfloat16* base = TAB + (size_t)b * 101 * kT + g * kL;
    const uint4* pa = (const uint4*)(base + (size_t)ai * kT);
    const uint4* pb = (const uint4*)(base + (size_t)bi * kT);
    unsigned int ua[32], ub[32];
    #pragma unroll
    for (int i = 0; i < 8; ++i){
        uint4 va = pa[i]; uint4 vb = pb[i];
        ua[4*i]=va.x; ua[4*i+1]=va.y; ua[4*i+2]=va.z; ua[4*i+3]=va.w;
        ub[4*i]=vb.x; ub[4*i+1]=vb.y; ub[4*i+2]=vb.z; ub[4*i+3]=vb.w;
    }
    float Aa = 1.f, Cc = 0.f;   // q_out = Aa*q_in + Cc
    #pragma unroll
    for (int t = 0; t < kL; ++t){
        float ea = bfhalf(ua[t>>1], t & 1);
        float eb = bfhalf(ub[t>>1], t & 1);
        float rD = rcp_fast((1.f + ea) * (1.f + eb));
        float aq = ea * rD;
        Aa = aq * Aa;
        Cc = fmaf(aq, Cc, rD + rD);
    }
    if (valid){
        size_t idx = (size_t)(g * kB + b) * kM + j;
        A[idx] = __float2bfloat16(Aa);
        C[idx] = __float2bfloat16(Cc);
    }
}

// ---- density sigmoid + initial states + chunk compose (fused, q-space):
__global__ __launch_bounds__(256) void k_initB(const float* __restrict__ mesh,
        const float* __restrict__ dens_pre, const float* __restrict__ bout,
        const float* __restrict__ Wm, const float* __restrict__ bm,
        const float* __restrict__ ctxW, const float* __restrict__ Wo,
        const float* __restrict__ bo, float* __restrict__ dens,
        __hip_bfloat16* __restrict__ A, const __hip_bfloat16* __restrict__ C,
        float* __restrict__ out){
    __shared__ float w0s[kH], w1s[kH], w2s[kH], bcs[kH], wos[kH];
    int tid = threadIdx.x;
    int b = blockIdx.y;
    w0s[tid] = Wm[tid];
    w1s[tid] = Wm[kH + tid];
    w2s[tid] = Wm[2*kH + tid];
    bcs[tid] = bm[tid] + ctxW[b * kH + tid];
    wos[tid] = Wo[tid];
    __syncthreads();
    int j = blockIdx.x * 256 + tid;
    if (j >= kM) return;
    float d = 1.f / (1.f + expf(-(dens_pre[j] + bout[0])));
    if (b == 0) dens[j] = d;
    float be = mesh[2*j], al = mesh[2*j+1];
    float acc = 0.f;
    #pragma unroll 8
    for (int h = 0; h < kH; ++h){
        float pre = fmaf(be, w0s[h], fmaf(al, w1s[h], fmaf(d, w2s[h], bcs[h])));
        acc = fmaf(fmaxf(pre, 0.f), wos[h], acc);
    }
    float s = tanhf(acc + bo[0]);
    out[OFF_IS + b * kM + j] = s;
    float q = s + 1.f;
    #pragma unroll
    for (int g = 0; g < kG; ++g){
        size_t idx = (size_t)(g * kB + b) * kM + j;
        float a = __bfloat162float(A[idx]), c = __bfloat162float(C[idx]);
        A[idx] = __float2bfloat16(q);       // entry q for chunk g
        q = fmaf(a, q, c);
    }
}

// ---- scan pass 2: replay each chunk from entry q; bf16 LDS-transpose reduction.
__global__ __launch_bounds__(64) void k_scanC(const float* __restrict__ mesh,
        const float* __restrict__ dens, const __hip_bfloat16* __restrict__ qin,
        const __hip_bfloat16* __restrict__ TAB,
        __hip_bfloat16* __restrict__ partials, float* __restrict__ out){
    __shared__ __hip_bfloat16 cb[kL * 66];
    int L = threadIdx.x;
    int jw = blockIdx.x, g = blockIdx.y, b = blockIdx.z;
    int j = jw * 64 + L;
    bool valid = j < kM;
    int jj = valid ? j : 0;
    float d  = valid ? dens[j] : 0.f;
    float q  = valid ? __bfloat162float(qin[(size_t)(g * kB + b) * kM + j]) : 0.f;
    float be = mesh[2*jj], al = mesh[2*jj+1];
    int ai = __float2int_rn(al * 100.f);
    int bi = __float2int_rn(be * 100.f);
    const __hip_bfloat16* base = TAB + (size_t)b * 101 * kT + g * kL;
    const uint4* pa = (const uint4*)(base + (size_t)ai * kT);
    const uint4* pb = (const uint4*)(base + (size_t)bi * kT);
    unsigned int ua[32], ub[32];
    #pragma unroll
    for (int i = 0; i < 8; ++i){
        uint4 va = pa[i]; uint4 vb = pb[i];
        ua[4*i]=va.x; ua[4*i+1]=va.y; ua[4*i+2]=va.z; ua[4*i+3]=va.w;
        ub[4*i]=vb.x; ub[4*i+1]=vb.y; ub[4*i+2]=vb.z; ub[4*i+3]=vb.w;
    }
    if (valid && g == 0){
        out[OFF_DENS + b * kM + j] = d;
        out[OFF_MESH + 2 * (b * kM + j)]     = be;
        out[OFF_MESH + 2 * (b * kM + j) + 1] = al;
    }
    #pragma unroll
    for (int t = 0; t < kL; ++t){
        float ea = bfhalf(ua[t>>1], t & 1);
        float eb = bfhalf(ub[t>>1], t & 1);
        float rD = rcp_fast((1.f + ea) * (1.f + eb));
        q = fmaf(ea, q, 2.f) * rD;
        cb[t * 66 + L] = __float2bfloat16(fmaf(d, q, -d));   // d*s = d*q - d
    }
    __syncthreads();
    float a0 = 0.f, a1 = 0.f;
    const __hip_bfloat162* row = (const __hip_bfloat162*)&cb[L * 66];
    #pragma unroll
    for (int i = 0; i < 32; ++i){
        float2 f = __bfloat1622float2(row[i]);
        a0 += f.x; a1 += f.y;
    }
    partials[(size_t)(b * kJW + jw) * kT + g * kL + L] = __float2bfloat16(a0 + a1);
}

// ---- finalize: per-block dsum; m = sum(partials)/dsum; b_out = hs*h + ms*m + mo
__global__ __launch_bounds__(256) void k_final(const __hip_bfloat16* __restrict__ partials,
        const float* __restrict__ dens, const float* __restrict__ dec,
        const float* __restrict__ hsr, const float* __restrict__ msr,
        const float* __restrict__ mor, float* __restrict__ out){
    __shared__ float red[4];
    int tid = threadIdx.x;
    int b = blockIdx.y;
    float ds = 0.f;
    for (int i = tid; i < kM; i += 256) ds += dens[i];
    #pragma unroll
    for (int off = 32; off; off >>= 1) ds += __shfl_down(ds, off, 64);
    if ((tid & 63) == 0) red[tid >> 6] = ds;
    __syncthreads();
    float dsum = red[0] + red[1] + red[2] + red[3];
    int t = blockIdx.x * 256 + tid;   // grid.x = 4
    float acc = 0.f;
    const __hip_bfloat16* p = partials + (size_t)b * kJW * kT + t;
    #pragma unroll 4
    for (int w = 0; w < kJW; ++w) acc += __bfloat162float(p[(size_t)w * kT]);
    float m = acc / dsum;
    float hscale = 10.f / (1.f + expf(-hsr[0]));
    float mscale = 10.f / (1.f + expf(-msr[0]));
    float moff   = -10.f + 20.f / (1.f + expf(-mor[0]));
    float h = dec[b * kT + t];
    out[OFF_M + b * kT + t]    = m;
    out[OFF_BOUT + b * kT + t] = fmaf(hscale, h, fmaf(mscale, m, moff));
}

extern "C" void kernel_launch(void* const* d_in, const int* in_sizes, int n_in,
                              void* d_out, int out_size, void* d_ws, size_t ws_size,
                              hipStream_t stream) {
    (void)in_sizes; (void)n_in; (void)out_size; (void)ws_size;
    const float* enc_in = (const float*)d_in[0];
    const float* dec    = (const float*)d_in[1];
    const float* mask   = (const float*)d_in[2];
    const float* mesh   = (const float*)d_in[3];
    const float* Win    = (const float*)d_in[4];
    const float* bin    = (const float*)d_in[5];
    const float* Wr     = (const float*)d_in[6];
    const float* br     = (const float*)d_in[7];
    const float* Wout   = (const float*)d_in[8];
    const float* bout   = (const float*)d_in[9];
    const float* Ws     = (const float*)d_in[10];
    const float* bs     = (const float*)d_in[11];
    const float* Wm     = (const float*)d_in[12];
    const float* Wc     = (const float*)d_in[13];
    const float* bm     = (const float*)d_in[14];
    const float* Wo     = (const float*)d_in[15];
    const float* bo     = (const float*)d_in[16];
    const float* hsr    = (const float*)d_in[17];
    const float* msr    = (const float*)d_in[18];
    const float* mor    = (const float*)d_in[19];
    float* out = (float*)d_out;

    float* ws = (float*)d_ws;
    float* x1    = ws + WS_X1;
    float* x2    = ws + WS_X2;
    float* densv = ws + WS_DENS;
    float* densp = ws + WS_DENSP;
    float* ctxW  = ws + WS_CTXW;
    __hip_bfloat16* TAB      = (__hip_bfloat16*)(ws + WS_TAB);
    __hip_bfloat16* A        = (__hip_bfloat16*)(ws + WS_A);
    __hip_bfloat16* C        = (__hip_bfloat16*)(ws + WS_C);
    __hip_bfloat16* partials = (__hip_bfloat16*)(ws + WS_PART);

    k_enc         <<<dim3(kB),          256, 0, stream>>>(enc_in, mask, Ws, bs, Wc, ctxW, densp);
    k_res_first   <<<dim3(161, 4),      256, 0, stream>>>(mesh, Win, bin, Wr, br, x1);
    k_res_t<false><<<dim3(161, 4),      256, 0, stream>>>(x1, Wr + 65536,  br + 256, x2, nullptr, nullptr);
    k_res_t<true> <<<dim3(161, 4),      256, 0, stream>>>(x2, Wr + 131072, br + 512, nullptr, Wout, densp);
    k_tab         <<<dim3(4, 101, kB),  256, 0, stream>>>(dec, TAB);   // x1 dead -> TAB aliases it
    k_scanA       <<<dim3(21, kG, kB),  256, 0, stream>>>(mesh, TAB, A, C);
    k_initB       <<<dim3(21, kB),      256, 0, stream>>>(mesh, densp, bout, Wm, bm, ctxW, Wo, bo, densv, A, C, out);
    k_scanC       <<<dim3(kJW, kG, kB),  64, 0, stream>>>(mesh, densv, A, TAB, partials, out);
    k_final       <<<dim3(4, kB),       256, 0, stream>>>(partials, densv, dec, hsr, msr, mor, out);
}

// Round 10
// 270.755 us; speedup vs baseline: 2.2517x; 1.0460x over previous
//
#include <hip/hip_runtime.h>
#include <hip/hip_bf16.h>
#include <math.h>

constexpr int kB = 16;
constexpr int kS = 256;
constexpr int kT = 1024;
constexpr int kM = 5151;
constexpr int kH = 256;
constexpr int kG = 16;                   // t-chunks (inside k_scan)
constexpr int kL = 64;                   // t's per chunk
constexpr int kJW = 84;                  // ceil(M/64) j-waves
constexpr float kSig = 1442.6950408889634f; // 1000 * log2(e)
constexpr float kAiS = 14.426950408889634f; // kSig / 100 (per alpha-index)
constexpr float kClamp = 1e16f;          // exp clamp: products stay < fp32 max (1e32)

constexpr int OFF_BOUT = 0;
constexpr int OFF_DENS = kB * kT;                 // 16384
constexpr int OFF_M    = OFF_DENS + kB * kM;      // 98800
constexpr int OFF_IS   = OFF_M + kB * kT;         // 115184
constexpr int OFF_MESH = OFF_IS + kB * kM;        // 197600

// workspace layout (float-slot offsets). ws_size = 256 MiB (proven: harness poison
// fillBufferAligned writes 262144 KB in one dispatch). Total used: ~17.1 MB.
constexpr int WS_TAB  = 0;        // 1654784 bf16 = 827392 float slots
constexpr int WS_X1   = 851968;   // 1318656 fp32 -> end 2170624
constexpr int WS_X2   = 2170624;  // 1318656 fp32 -> end 3489280
constexpr int WS_ISF  = 3489280;  // 82416 fp32   -> end 3571696
constexpr int WS_PART = 3571712;  // 1376256 bf16 = 688128 slots -> end 4259840
constexpr int WS_DENS = 4259840;  // 5376
constexpr int WS_DENSP= 4265216;  // 5376 (end 4270592 floats = 17.1 MB << 256 MiB)

__device__ __forceinline__ float exp2_fast(float x){ return __builtin_amdgcn_exp2f(x); }
__device__ __forceinline__ float rcp_fast(float x){ return __builtin_amdgcn_rcpf(x); }

// ---- sigmoid-exponential table: TAB[b][ai][t] = min(exp2(ai*kAiS - h[b][t]*kSig), 1e16)
// eu(alpha_j) = TAB[b][ai_j][t]; ed(beta_j) = 1/TAB[b][bi_j][t] (exact identity).
// Also zeroes dens_pre (launch #1; stream-ordered before res3's atomics).
__global__ __launch_bounds__(256) void k_tab(const float* __restrict__ dec,
        __hip_bfloat16* __restrict__ TAB, float* __restrict__ dens_pre){
    int t  = blockIdx.x * 256 + threadIdx.x;   // grid.x = 4
    int ai = blockIdx.y;                        // 101
    int b  = blockIdx.z;                        // 16
    if (ai == 0 && b == 0){
        for (int i = t; i < 5376; i += 1024) dens_pre[i] = 0.f;
    }
    float hts = dec[b * kT + t] * kSig;
    float v = fminf(exp2_fast(fmaf((float)ai, kAiS, -hts)), kClamp);
    TAB[(size_t)(b * 101 + ai) * kT + t] = __float2bfloat16(v);
}

// ---- first residual layer fused with input layer. 32j x 64o tile, grid 161x4.
__global__ __launch_bounds__(256) void k_res_first(const float* __restrict__ mesh,
        const float* __restrict__ Win, const float* __restrict__ bin,
        const float* __restrict__ Wl, const float* __restrict__ bl,
        float* __restrict__ xout){
    __shared__ float xT[64 * 34];   // [k][j], stride 34 (8B-aligned float2 reads)
    __shared__ float Wsh[64 * 64];  // [k][o], conflict-free both directions
    __shared__ float beL[32], alL[32];
    int tid = threadIdx.x;
    int og = tid & 31, pg = tid >> 5;       // 2 outs, 4 points per thread
    int jb = blockIdx.x * 32;
    int ob = blockIdx.y * 64;
    if (tid < 32){
        int jg = jb + tid;
        beL[tid] = (jg < kM) ? mesh[2*jg]   : 0.f;
        alL[tid] = (jg < kM) ? mesh[2*jg+1] : 0.f;
    }
    __syncthreads();
    float acc[4][2] = {};
    int ks = tid & 63;    // staging k: constant per thread
    int j0 = tid >> 6;    // staging j base: 0..3
    for (int sl = 0; sl < 4; ++sl){
        int kb = sl * 64;
        float w0k = Win[kb + ks], w1k = Win[kH + kb + ks], bk = bin[kb + ks];
        #pragma unroll
        for (int it = 0; it < 8; ++it){
            int j = j0 + it * 4;
            xT[ks * 34 + j] = fmaxf(fmaf(beL[j], w0k, fmaf(alL[j], w1k, bk)), 0.f);
        }
        #pragma unroll
        for (int it = 0; it < 16; ++it){
            int idx = tid + it * 256;
            int o = idx & 63, k = idx >> 6;
            Wsh[k * 64 + o] = Wl[(kb + k) * kH + ob + o];
        }
        __syncthreads();
        #pragma unroll 4
        for (int k = 0; k < 64; ++k){
            float2 x01 = *(const float2*)&xT[k * 34 + pg * 4];
            float2 x23 = *(const float2*)&xT[k * 34 + pg * 4 + 2];
            float w0 = Wsh[k * 64 + og];
            float w1 = Wsh[k * 64 + og + 32];
            acc[0][0] = fmaf(x01.x, w0, acc[0][0]); acc[0][1] = fmaf(x01.x, w1, acc[0][1]);
            acc[1][0] = fmaf(x01.y, w0, acc[1][0]); acc[1][1] = fmaf(x01.y, w1, acc[1][1]);
            acc[2][0] = fmaf(x23.x, w0, acc[2][0]); acc[2][1] = fmaf(x23.x, w1, acc[2][1]);
            acc[3][0] = fmaf(x23.y, w0, acc[3][0]); acc[3][1] = fmaf(x23.y, w1, acc[3][1]);
        }
        __syncthreads();
    }
    #pragma unroll
    for (int i = 0; i < 4; ++i){
        int jl = pg * 4 + i;
        int jg = jb + jl;
        if (jg >= kM) continue;
        float be = beL[jl], al = alL[jl];
        #pragma unroll
        for (int r = 0; r < 2; ++r){
            int o = ob + og + 32 * r;
            float x0v = fmaxf(fmaf(be, Win[o], fmaf(al, Win[kH + o], bin[o])), 0.f);
            float v = acc[i][r] + bl[o];
            xout[jg * kH + o] = x0v + fmaxf(v, 0.f);
        }
    }
}

// ---- residual layer, 32j x 64o tile. kDOT=false: xout = xin + relu(xin@W+b).
// kDOT=true: no xout; accumulate density logits (x3 . Wout slice) into dens_pre.
template<bool kDOT>
__global__ __launch_bounds__(256) void k_res_t(const float* __restrict__ xin,
        const float* __restrict__ Wl, const float* __restrict__ bl,
        float* __restrict__ xout, const float* __restrict__ Wout,
        float* __restrict__ dens_pre){
    __shared__ float xT[64 * 34];
    __shared__ float Wsh[64 * 64];
    int tid = threadIdx.x;
    int og = tid & 31, pg = tid >> 5;
    int jb = blockIdx.x * 32;
    int ob = blockIdx.y * 64;
    float acc[4][2] = {};
    int ks = tid & 63;
    int j0 = tid >> 6;
    for (int sl = 0; sl < 4; ++sl){
        int kb = sl * 64;
        #pragma unroll
        for (int it = 0; it < 8; ++it){
            int j = j0 + it * 4;
            int jg = jb + j;
            xT[ks * 34 + j] = (jg < kM) ? xin[jg * kH + kb + ks] : 0.f;
        }
        #pragma unroll
        for (int it = 0; it < 16; ++it){
            int idx = tid + it * 256;
            int o = idx & 63, k = idx >> 6;
            Wsh[k * 64 + o] = Wl[(kb + k) * kH + ob + o];
        }
        __syncthreads();
        #pragma unroll 4
        for (int k = 0; k < 64; ++k){
            float2 x01 = *(const float2*)&xT[k * 34 + pg * 4];
            float2 x23 = *(const float2*)&xT[k * 34 + pg * 4 + 2];
            float w0 = Wsh[k * 64 + og];
            float w1 = Wsh[k * 64 + og + 32];
            acc[0][0] = fmaf(x01.x, w0, acc[0][0]); acc[0][1] = fmaf(x01.x, w1, acc[0][1]);
            acc[1][0] = fmaf(x01.y, w0, acc[1][0]); acc[1][1] = fmaf(x01.y, w1, acc[1][1]);
            acc[2][0] = fmaf(x23.x, w0, acc[2][0]); acc[2][1] = fmaf(x23.x, w1, acc[2][1]);
            acc[3][0] = fmaf(x23.y, w0, acc[3][0]); acc[3][1] = fmaf(x23.y, w1, acc[3][1]);
        }
        __syncthreads();
    }
    float wo0 = 0.f, wo1 = 0.f;
    if (kDOT){ wo0 = Wout[ob + og]; wo1 = Wout[ob + og + 32]; }
    #pragma unroll
    for (int i = 0; i < 4; ++i){
        int jg = jb + pg * 4 + i;
        float v0 = 0.f, v1 = 0.f;
        if (jg < kM){
            float a0 = acc[i][0] + bl[ob + og];
            float a1 = acc[i][1] + bl[ob + og + 32];
            v0 = xin[jg * kH + ob + og]      + fmaxf(a0, 0.f);
            v1 = xin[jg * kH + ob + og + 32] + fmaxf(a1, 0.f);
            if (!kDOT){
                xout[jg * kH + ob + og]      = v0;
                xout[jg * kH + ob + og + 32] = v1;
            }
        }
        if (kDOT){
            float p = fmaf(v0, wo0, v1 * wo1);   // zero for invalid jg
            p += __shfl_down(p, 16, 64);
            p += __shfl_down(p, 8, 64);
            p += __shfl_down(p, 4, 64);
            p += __shfl_down(p, 2, 64);
            p += __shfl_down(p, 1, 64);
            if (og == 0 && jg < kM) atomicAdd(&dens_pre[jg], p);
        }
    }
}

// ---- fused: encoder context (recomputed per block) + density sigmoid + initial states.
// ctx = masked-mean(relu(enc_in@Ws+bs)); cw = ctx@Wc (this thread's h column);
// d = sigmoid(densp+bout); is = tanh(relu(mesh_feat@Wm + cw + bm)@Wo + bo).
__global__ __launch_bounds__(256) void k_init(const float* __restrict__ enc_in,
        const float* __restrict__ mask, const float* __restrict__ Ws,
        const float* __restrict__ bs, const float* __restrict__ Wc,
        const float* __restrict__ mesh, const float* __restrict__ dens_pre,
        const float* __restrict__ bout, const float* __restrict__ Wm,
        const float* __restrict__ bm, const float* __restrict__ Wo,
        const float* __restrict__ bo, float* __restrict__ dens,
        float* __restrict__ isf, float* __restrict__ out){
    __shared__ float ctx_l[kH];
    __shared__ float w0s[kH], w1s[kH], w2s[kH], bcs[kH], wos[kH];
    int tid = threadIdx.x;
    int b = blockIdx.y;
    // encoder context (identical math to the old k_enc)
    {
        float w0 = Ws[tid], w1 = Ws[kH + tid], bh = bs[tid];
        float acc = 0.f, msum = 0.f;
        const float* e = enc_in + b * kS * 2;
        const float* mk = mask + b * kS;
        #pragma unroll 4
        for (int s = 0; s < kS; ++s){
            float e0 = e[2*s], e1 = e[2*s+1], mm = mk[s];
            float v = fmaxf(fmaf(e0, w0, fmaf(e1, w1, bh)), 0.f);
            acc = fmaf(v, mm, acc);
            msum += mm;
        }
        ctx_l[tid] = acc / fmaxf(msum, 1.f);
    }
    __syncthreads();
    float cw = 0.f;
    #pragma unroll 8
    for (int k = 0; k < kH; ++k) cw = fmaf(ctx_l[k], Wc[k * kH + tid], cw);
    w0s[tid] = Wm[tid];
    w1s[tid] = Wm[kH + tid];
    w2s[tid] = Wm[2*kH + tid];
    bcs[tid] = bm[tid] + cw;
    wos[tid] = Wo[tid];
    __syncthreads();
    int j = blockIdx.x * 256 + tid;
    if (j >= kM) return;
    float d = 1.f / (1.f + expf(-(dens_pre[j] + bout[0])));
    if (b == 0) dens[j] = d;
    float be = mesh[2*j], al = mesh[2*j+1];
    float acc = 0.f;
    #pragma unroll 8
    for (int h = 0; h < kH; ++h){
        float pre = fmaf(be, w0s[h], fmaf(al, w1s[h], fmaf(d, w2s[h], bcs[h])));
        acc = fmaf(fmaxf(pre, 0.f), wos[h], acc);
    }
    float s = tanhf(acc + bo[0]);
    isf[b * kM + j] = s;
    out[OFF_IS + b * kM + j] = s;
}

__device__ __forceinline__ float bfhalf(unsigned int w, int odd){
    return __uint_as_float(odd ? (w & 0xffff0000u) : (w << 16));
}

// ---- single-pass relay scan: one wave owns 64 j's for ALL 1024 t (q = s+1 space;
// q' = (ea*q + 2)/((1+ea)(1+eb)), ea/eb from TAB). Every 64 t: bf16 LDS transpose ->
// lane L holds the wave's 64-point partial for t = g*64+L -> one bf16 store.
__global__ __launch_bounds__(64) void k_scan(const float* __restrict__ mesh,
        const float* __restrict__ dens, const float* __restrict__ isf,
        const __hip_bfloat16* __restrict__ TAB,
        __hip_bfloat16* __restrict__ partials, float* __restrict__ out){
    __shared__ __hip_bfloat16 cb[kL * 66];
    int L = threadIdx.x;
    int jw = blockIdx.x, b = blockIdx.y;
    int j = jw * 64 + L;
    bool valid = j < kM;
    int jj = valid ? j : 0;
    float d  = valid ? dens[j] : 0.f;
    float q  = valid ? isf[b * kM + j] + 1.f : 0.f;
    float be = mesh[2*jj], al = mesh[2*jj+1];
    int ai = __float2int_rn(al * 100.f);
    int bi = __float2int_rn(be * 100.f);
    const __hip_bfloat16* ra = TAB + (size_t)(b * 101 + ai) * kT;
    const __hip_bfloat16* rb = TAB + (size_t)(b * 101 + bi) * kT;
    if (valid){
        out[OFF_DENS + b * kM + j] = d;
        out[OFF_MESH + 2 * (b * kM + j)]     = be;
        out[OFF_MESH + 2 * (b * kM + j) + 1] = al;
    }
    size_t pbase = (size_t)(b * kJW + jw) * kT + L;
    for (int g = 0; g < kG; ++g){
        const uint4* pa = (const uint4*)(ra + g * kL);
        const uint4* pb = (const uint4*)(rb + g * kL);
        unsigned int ua[32], ub[32];
        #pragma unroll
        for (int i = 0; i < 8; ++i){
            uint4 va = pa[i]; uint4 vb = pb[i];
            ua[4*i]=va.x; ua[4*i+1]=va.y; ua[4*i+2]=va.z; ua[4*i+3]=va.w;
            ub[4*i]=vb.x; ub[4*i+1]=vb.y; ub[4*i+2]=vb.z; ub[4*i+3]=vb.w;
        }
        #pragma unroll
        for (int t = 0; t < kL; ++t){
            float ea = bfhalf(ua[t>>1], t & 1);
            float eb = bfhalf(ub[t>>1], t & 1);
            float rD = rcp_fast((1.f + ea) * (1.f + eb));   // q-independent, pipelines ahead
            q = fmaf(ea, q, 2.f) * rD;
            cb[t * 66 + L] = __float2bfloat16(fmaf(d, q, -d));   // d*s = d*q - d
        }
        __syncthreads();
        float a0 = 0.f, a1 = 0.f;
        const __hip_bfloat162* row = (const __hip_bfloat162*)&cb[L * 66];
        #pragma unroll
        for (int i = 0; i < 32; ++i){
            float2 f = __bfloat1622float2(row[i]);
            a0 += f.x; a1 += f.y;
        }
        partials[pbase + g * kL] = __float2bfloat16(a0 + a1);
        __syncthreads();
    }
}

// ---- finalize: per-block dsum; m = sum(partials)/dsum; b_out = hs*h + ms*m + mo
__global__ __launch_bounds__(256) void k_final(const __hip_bfloat16* __restrict__ partials,
        const float* __restrict__ dens, const float* __restrict__ dec,
        const float* __restrict__ hsr, const float* __restrict__ msr,
        const float* __restrict__ mor, float* __restrict__ out){
    __shared__ float red[4];
    int tid = threadIdx.x;
    int b = blockIdx.y;
    float ds = 0.f;
    for (int i = tid; i < kM; i += 256) ds += dens[i];
    #pragma unroll
    for (int off = 32; off; off >>= 1) ds += __shfl_down(ds, off, 64);
    if ((tid & 63) == 0) red[tid >> 6] = ds;
    __syncthreads();
    float dsum = red[0] + red[1] + red[2] + red[3];
    int t = blockIdx.x * 256 + tid;   // grid.x = 4
    float acc = 0.f;
    const __hip_bfloat16* p = partials + (size_t)b * kJW * kT + t;
    #pragma unroll 4
    for (int w = 0; w < kJW; ++w) acc += __bfloat162float(p[(size_t)w * kT]);
    float m = acc / dsum;
    float hscale = 10.f / (1.f + expf(-hsr[0]));
    float mscale = 10.f / (1.f + expf(-msr[0]));
    float moff   = -10.f + 20.f / (1.f + expf(-mor[0]));
    float h = dec[b * kT + t];
    out[OFF_M + b * kT + t]    = m;
    out[OFF_BOUT + b * kT + t] = fmaf(hscale, h, fmaf(mscale, m, moff));
}

extern "C" void kernel_launch(void* const* d_in, const int* in_sizes, int n_in,
                              void* d_out, int out_size, void* d_ws, size_t ws_size,
                              hipStream_t stream) {
    (void)in_sizes; (void)n_in; (void)out_size; (void)ws_size;
    const float* enc_in = (const float*)d_in[0];
    const float* dec    = (const float*)d_in[1];
    const float* mask   = (const float*)d_in[2];
    const float* mesh   = (const float*)d_in[3];
    const float* Win    = (const float*)d_in[4];
    const float* bin    = (const float*)d_in[5];
    const float* Wr     = (const float*)d_in[6];
    const float* br     = (const float*)d_in[7];
    const float* Wout   = (const float*)d_in[8];
    const float* bout   = (const float*)d_in[9];
    const float* Ws     = (const float*)d_in[10];
    const float* bs     = (const float*)d_in[11];
    const float* Wm     = (const float*)d_in[12];
    const float* Wc     = (const float*)d_in[13];
    const float* bm     = (const float*)d_in[14];
    const float* Wo     = (const float*)d_in[15];
    const float* bo     = (const float*)d_in[16];
    const float* hsr    = (const float*)d_in[17];
    const float* msr    = (const float*)d_in[18];
    const float* mor    = (const float*)d_in[19];
    float* out = (float*)d_out;

    float* ws = (float*)d_ws;
    __hip_bfloat16* TAB      = (__hip_bfloat16*)(ws + WS_TAB);
    float* x1    = ws + WS_X1;
    float* x2    = ws + WS_X2;
    float* isf   = ws + WS_ISF;
    __hip_bfloat16* partials = (__hip_bfloat16*)(ws + WS_PART);
    float* densv = ws + WS_DENS;
    float* densp = ws + WS_DENSP;

    k_tab         <<<dim3(4, 101, kB),  256, 0, stream>>>(dec, TAB, densp);
    k_res_first   <<<dim3(161, 4),      256, 0, stream>>>(mesh, Win, bin, Wr, br, x1);
    k_res_t<false><<<dim3(161, 4),      256, 0, stream>>>(x1, Wr + 65536,  br + 256, x2, nullptr, nullptr);
    k_res_t<true> <<<dim3(161, 4),      256, 0, stream>>>(x2, Wr + 131072, br + 512, nullptr, Wout, densp);
    k_init        <<<dim3(21, kB),      256, 0, stream>>>(enc_in, mask, Ws, bs, Wc, mesh, densp,
                                                          bout, Wm, bm, Wo, bo, densv, isf, out);
    k_scan        <<<dim3(kJW, kB),      64, 0, stream>>>(mesh, densv, isf, TAB, partials, out);
    k_final       <<<dim3(4, kB),       256, 0, stream>>>(partials, densv, dec, hsr, msr, mor, out);
}

// Round 11
// 265.274 us; speedup vs baseline: 2.2982x; 1.0207x over previous
//
#include <hip/hip_runtime.h>
#include <hip/hip_bf16.h>
#include <math.h>

constexpr int kB = 16;
constexpr int kS = 256;
constexpr int kT = 1024;
constexpr int kM = 5151;
constexpr int kH = 256;
constexpr int kG = 16;                   // t-chunks (inside k_scan)
constexpr int kL = 64;                   // t's per chunk
constexpr int kJW = 84;                  // ceil(M/64) j-waves
constexpr float kSig = 1442.6950408889634f; // 1000 * log2(e)
constexpr float kAiS = 14.426950408889634f; // kSig / 100 (per alpha-index)
constexpr float kClamp = 1e16f;          // exp clamp: products stay < fp32 max (1e32)

constexpr int OFF_BOUT = 0;
constexpr int OFF_DENS = kB * kT;                 // 16384
constexpr int OFF_M    = OFF_DENS + kB * kM;      // 98800
constexpr int OFF_IS   = OFF_M + kB * kT;         // 115184
constexpr int OFF_MESH = OFF_IS + kB * kM;        // 197600

// workspace layout (float-slot offsets). ws_size = 256 MiB (proven by harness poison).
constexpr int WS_TAB  = 0;        // 1654784 bf16 = 827392 float slots
constexpr int WS_X1   = 851968;   // 1318656 fp32 -> end 2170624
constexpr int WS_X2   = 2170624;  // 1318656 fp32 -> end 3489280
constexpr int WS_ISF  = 3489280;  // 82416 fp32   -> end 3571696
constexpr int WS_PART = 3571712;  // 1376256 bf16 -> end 4259840
constexpr int WS_DENS = 4259840;  // 5376
constexpr int WS_DENSP= 4265216;  // 5376 (end 4270592 floats = 17.1 MB << 256 MiB)

__device__ __forceinline__ float exp2_fast(float x){ return __builtin_amdgcn_exp2f(x); }
__device__ __forceinline__ float rcp_fast(float x){ return __builtin_amdgcn_rcpf(x); }

// ---- sigmoid-exponential table: TAB[b][ai][t] = min(exp2(ai*kAiS - h[b][t]*kSig), 1e16)
// Also zeroes dens_pre (launch #1; stream-ordered before res3's atomics).
__global__ __launch_bounds__(256) void k_tab(const float* __restrict__ dec,
        __hip_bfloat16* __restrict__ TAB, float* __restrict__ dens_pre){
    int t  = blockIdx.x * 256 + threadIdx.x;   // grid.x = 4
    int ai = blockIdx.y;                        // 101
    int b  = blockIdx.z;                        // 16
    if (ai == 0 && b == 0){
        for (int i = t; i < 5376; i += 1024) dens_pre[i] = 0.f;
    }
    float hts = dec[b * kT + t] * kSig;
    float v = fminf(exp2_fast(fmaf((float)ai, kAiS, -hts)), kClamp);
    TAB[(size_t)(b * 101 + ai) * kT + t] = __float2bfloat16(v);
}

// ---- first residual layer fused with input layer. 32j x 64o tile, grid 161x4.
__global__ __launch_bounds__(256) void k_res_first(const float* __restrict__ mesh,
        const float* __restrict__ Win, const float* __restrict__ bin,
        const float* __restrict__ Wl, const float* __restrict__ bl,
        float* __restrict__ xout){
    __shared__ float xT[64 * 34];   // [k][j], stride 34 (8B-aligned float2 reads)
    __shared__ float Wsh[64 * 64];  // [k][o], conflict-free both directions
    __shared__ float beL[32], alL[32];
    int tid = threadIdx.x;
    int og = tid & 31, pg = tid >> 5;       // 2 outs, 4 points per thread
    int jb = blockIdx.x * 32;
    int ob = blockIdx.y * 64;
    if (tid < 32){
        int jg = jb + tid;
        beL[tid] = (jg < kM) ? mesh[2*jg]   : 0.f;
        alL[tid] = (jg < kM) ? mesh[2*jg+1] : 0.f;
    }
    __syncthreads();
    float acc[4][2] = {};
    int ks = tid & 63;    // staging k: constant per thread
    int j0 = tid >> 6;    // staging j base: 0..3
    for (int sl = 0; sl < 4; ++sl){
        int kb = sl * 64;
        float w0k = Win[kb + ks], w1k = Win[kH + kb + ks], bk = bin[kb + ks];
        #pragma unroll
        for (int it = 0; it < 8; ++it){
            int j = j0 + it * 4;
            xT[ks * 34 + j] = fmaxf(fmaf(beL[j], w0k, fmaf(alL[j], w1k, bk)), 0.f);
        }
        #pragma unroll
        for (int it = 0; it < 16; ++it){
            int idx = tid + it * 256;
            int o = idx & 63, k = idx >> 6;
            Wsh[k * 64 + o] = Wl[(kb + k) * kH + ob + o];
        }
        __syncthreads();
        #pragma unroll 4
        for (int k = 0; k < 64; ++k){
            float2 x01 = *(const float2*)&xT[k * 34 + pg * 4];
            float2 x23 = *(const float2*)&xT[k * 34 + pg * 4 + 2];
            float w0 = Wsh[k * 64 + og];
            float w1 = Wsh[k * 64 + og + 32];
            acc[0][0] = fmaf(x01.x, w0, acc[0][0]); acc[0][1] = fmaf(x01.x, w1, acc[0][1]);
            acc[1][0] = fmaf(x01.y, w0, acc[1][0]); acc[1][1] = fmaf(x01.y, w1, acc[1][1]);
            acc[2][0] = fmaf(x23.x, w0, acc[2][0]); acc[2][1] = fmaf(x23.x, w1, acc[2][1]);
            acc[3][0] = fmaf(x23.y, w0, acc[3][0]); acc[3][1] = fmaf(x23.y, w1, acc[3][1]);
        }
        __syncthreads();
    }
    #pragma unroll
    for (int i = 0; i < 4; ++i){
        int jl = pg * 4 + i;
        int jg = jb + jl;
        if (jg >= kM) continue;
        float be = beL[jl], al = alL[jl];
        #pragma unroll
        for (int r = 0; r < 2; ++r){
            int o = ob + og + 32 * r;
            float x0v = fmaxf(fmaf(be, Win[o], fmaf(al, Win[kH + o], bin[o])), 0.f);
            float v = acc[i][r] + bl[o];
            xout[jg * kH + o] = x0v + fmaxf(v, 0.f);
        }
    }
}

// ---- residual layer, 32j x 64o tile. kDOT=false: xout = xin + relu(xin@W+b).
// kDOT=true: no xout; accumulate density logits (x3 . Wout slice) into dens_pre.
template<bool kDOT>
__global__ __launch_bounds__(256) void k_res_t(const float* __restrict__ xin,
        const float* __restrict__ Wl, const float* __restrict__ bl,
        float* __restrict__ xout, const float* __restrict__ Wout,
        float* __restrict__ dens_pre){
    __shared__ float xT[64 * 34];
    __shared__ float Wsh[64 * 64];
    int tid = threadIdx.x;
    int og = tid & 31, pg = tid >> 5;
    int jb = blockIdx.x * 32;
    int ob = blockIdx.y * 64;
    float acc[4][2] = {};
    int ks = tid & 63;
    int j0 = tid >> 6;
    for (int sl = 0; sl < 4; ++sl){
        int kb = sl * 64;
        #pragma unroll
        for (int it = 0; it < 8; ++it){
            int j = j0 + it * 4;
            int jg = jb + j;
            xT[ks * 34 + j] = (jg < kM) ? xin[jg * kH + kb + ks] : 0.f;
        }
        #pragma unroll
        for (int it = 0; it < 16; ++it){
            int idx = tid + it * 256;
            int o = idx & 63, k = idx >> 6;
            Wsh[k * 64 + o] = Wl[(kb + k) * kH + ob + o];
        }
        __syncthreads();
        #pragma unroll 4
        for (int k = 0; k < 64; ++k){
            float2 x01 = *(const float2*)&xT[k * 34 + pg * 4];
            float2 x23 = *(const float2*)&xT[k * 34 + pg * 4 + 2];
            float w0 = Wsh[k * 64 + og];
            float w1 = Wsh[k * 64 + og + 32];
            acc[0][0] = fmaf(x01.x, w0, acc[0][0]); acc[0][1] = fmaf(x01.x, w1, acc[0][1]);
            acc[1][0] = fmaf(x01.y, w0, acc[1][0]); acc[1][1] = fmaf(x01.y, w1, acc[1][1]);
            acc[2][0] = fmaf(x23.x, w0, acc[2][0]); acc[2][1] = fmaf(x23.x, w1, acc[2][1]);
            acc[3][0] = fmaf(x23.y, w0, acc[3][0]); acc[3][1] = fmaf(x23.y, w1, acc[3][1]);
        }
        __syncthreads();
    }
    float wo0 = 0.f, wo1 = 0.f;
    if (kDOT){ wo0 = Wout[ob + og]; wo1 = Wout[ob + og + 32]; }
    #pragma unroll
    for (int i = 0; i < 4; ++i){
        int jg = jb + pg * 4 + i;
        float v0 = 0.f, v1 = 0.f;
        if (jg < kM){
            float a0 = acc[i][0] + bl[ob + og];
            float a1 = acc[i][1] + bl[ob + og + 32];
            v0 = xin[jg * kH + ob + og]      + fmaxf(a0, 0.f);
            v1 = xin[jg * kH + ob + og + 32] + fmaxf(a1, 0.f);
            if (!kDOT){
                xout[jg * kH + ob + og]      = v0;
                xout[jg * kH + ob + og + 32] = v1;
            }
        }
        if (kDOT){
            float p = fmaf(v0, wo0, v1 * wo1);   // zero for invalid jg
            p += __shfl_down(p, 16, 64);
            p += __shfl_down(p, 8, 64);
            p += __shfl_down(p, 4, 64);
            p += __shfl_down(p, 2, 64);
            p += __shfl_down(p, 1, 64);
            if (og == 0 && jg < kM) atomicAdd(&dens_pre[jg], p);
        }
    }
}

// ---- fused: encoder context (recomputed per block) + density sigmoid + initial states.
__global__ __launch_bounds__(256) void k_init(const float* __restrict__ enc_in,
        const float* __restrict__ mask, const float* __restrict__ Ws,
        const float* __restrict__ bs, const float* __restrict__ Wc,
        const float* __restrict__ mesh, const float* __restrict__ dens_pre,
        const float* __restrict__ bout, const float* __restrict__ Wm,
        const float* __restrict__ bm, const float* __restrict__ Wo,
        const float* __restrict__ bo, float* __restrict__ dens,
        float* __restrict__ isf, float* __restrict__ out){
    __shared__ float ctx_l[kH];
    __shared__ float w0s[kH], w1s[kH], w2s[kH], bcs[kH], wos[kH];
    int tid = threadIdx.x;
    int b = blockIdx.y;
    {
        float w0 = Ws[tid], w1 = Ws[kH + tid], bh = bs[tid];
        float acc = 0.f, msum = 0.f;
        const float* e = enc_in + b * kS * 2;
        const float* mk = mask + b * kS;
        #pragma unroll 4
        for (int s = 0; s < kS; ++s){
            float e0 = e[2*s], e1 = e[2*s+1], mm = mk[s];
            float v = fmaxf(fmaf(e0, w0, fmaf(e1, w1, bh)), 0.f);
            acc = fmaf(v, mm, acc);
            msum += mm;
        }
        ctx_l[tid] = acc / fmaxf(msum, 1.f);
    }
    __syncthreads();
    float cw = 0.f;
    #pragma unroll 8
    for (int k = 0; k < kH; ++k) cw = fmaf(ctx_l[k], Wc[k * kH + tid], cw);
    w0s[tid] = Wm[tid];
    w1s[tid] = Wm[kH + tid];
    w2s[tid] = Wm[2*kH + tid];
    bcs[tid] = bm[tid] + cw;
    wos[tid] = Wo[tid];
    __syncthreads();
    int j = blockIdx.x * 256 + tid;
    if (j >= kM) return;
    float d = 1.f / (1.f + expf(-(dens_pre[j] + bout[0])));
    if (b == 0) dens[j] = d;
    float be = mesh[2*j], al = mesh[2*j+1];
    float acc = 0.f;
    #pragma unroll 8
    for (int h = 0; h < kH; ++h){
        float pre = fmaf(be, w0s[h], fmaf(al, w1s[h], fmaf(d, w2s[h], bcs[h])));
        acc = fmaf(fmaxf(pre, 0.f), wos[h], acc);
    }
    float s = tanhf(acc + bo[0]);
    isf[b * kM + j] = s;
    out[OFF_IS + b * kM + j] = s;
}

__device__ __forceinline__ float bfhalf(unsigned int w, int odd){
    return __uint_as_float(odd ? (w & 0xffff0000u) : (w << 16));
}

// ---- single-pass relay scan with register double-buffer prefetch of TAB gathers.
// One wave owns 64 j's for all 1024 t. While chunk g computes, chunk g+1's 16
// dwordx4 gathers are in flight (compiler emits vmcnt(16)-style partial waits).
__global__ __launch_bounds__(64) void k_scan(const float* __restrict__ mesh,
        const float* __restrict__ dens, const float* __restrict__ isf,
        const __hip_bfloat16* __restrict__ TAB,
        __hip_bfloat16* __restrict__ partials, float* __restrict__ out){
    __shared__ __hip_bfloat16 cb[kL * 66];
    int L = threadIdx.x;
    int jw = blockIdx.x, b = blockIdx.y;
    int j = jw * 64 + L;
    bool valid = j < kM;
    int jj = valid ? j : 0;
    float d  = valid ? dens[j] : 0.f;
    float q  = valid ? isf[b * kM + j] + 1.f : 0.f;
    float be = mesh[2*jj], al = mesh[2*jj+1];
    int ai = __float2int_rn(al * 100.f);
    int bi = __float2int_rn(be * 100.f);
    const __hip_bfloat16* ra = TAB + (size_t)(b * 101 + ai) * kT;
    const __hip_bfloat16* rb = TAB + (size_t)(b * 101 + bi) * kT;
    if (valid){
        out[OFF_DENS + b * kM + j] = d;
        out[OFF_MESH + 2 * (b * kM + j)]     = be;
        out[OFF_MESH + 2 * (b * kM + j) + 1] = al;
    }
    size_t pbase = (size_t)(b * kJW + jw) * kT + L;

    unsigned int uaA[32], ubA[32], uaB[32], ubB[32];

    auto load_chunk = [&](int g, unsigned int* UA, unsigned int* UB){
        const uint4* pa = (const uint4*)(ra + g * kL);
        const uint4* pb = (const uint4*)(rb + g * kL);
        #pragma unroll
        for (int i = 0; i < 8; ++i){
            uint4 va = pa[i];
            UA[4*i]=va.x; UA[4*i+1]=va.y; UA[4*i+2]=va.z; UA[4*i+3]=va.w;
        }
        #pragma unroll
        for (int i = 0; i < 8; ++i){
            uint4 vb = pb[i];
            UB[4*i]=vb.x; UB[4*i+1]=vb.y; UB[4*i+2]=vb.z; UB[4*i+3]=vb.w;
        }
    };
    auto compute_chunk = [&](int g, const unsigned int* UA, const unsigned int* UB){
        #pragma unroll
        for (int t = 0; t < kL; ++t){
            float ea = bfhalf(UA[t>>1], t & 1);
            float eb = bfhalf(UB[t>>1], t & 1);
            float rD = rcp_fast((1.f + ea) * (1.f + eb));   // q-independent, pipelines
            q = fmaf(ea, q, 2.f) * rD;
            cb[t * 66 + L] = __float2bfloat16(fmaf(d, q, -d));   // d*s = d*q - d
        }
        __syncthreads();
        float a0 = 0.f, a1 = 0.f;
        const __hip_bfloat162* row = (const __hip_bfloat162*)&cb[L * 66];
        #pragma unroll
        for (int i = 0; i < 32; ++i){
            float2 f = __bfloat1622float2(row[i]);
            a0 += f.x; a1 += f.y;
        }
        partials[pbase + g * kL] = __float2bfloat16(a0 + a1);
        __syncthreads();
    };

    load_chunk(0, uaA, ubA);
    #pragma unroll 1
    for (int g = 0; g < kG; g += 2){
        load_chunk(g + 1, uaB, ubB);          // prefetch odd chunk
        compute_chunk(g, uaA, ubA);
        if (g + 2 < kG) load_chunk(g + 2, uaA, ubA);   // prefetch next even chunk
        compute_chunk(g + 1, uaB, ubB);
    }
}

// ---- finalize: per-block dsum; m = sum(partials)/dsum; b_out = hs*h + ms*m + mo
__global__ __launch_bounds__(256) void k_final(const __hip_bfloat16* __restrict__ partials,
        const float* __restrict__ dens, const float* __restrict__ dec,
        const float* __restrict__ hsr, const float* __restrict__ msr,
        const float* __restrict__ mor, float* __restrict__ out){
    __shared__ float red[4];
    int tid = threadIdx.x;
    int b = blockIdx.y;
    float ds = 0.f;
    for (int i = tid; i < kM; i += 256) ds += dens[i];
    #pragma unroll
    for (int off = 32; off; off >>= 1) ds += __shfl_down(ds, off, 64);
    if ((tid & 63) == 0) red[tid >> 6] = ds;
    __syncthreads();
    float dsum = red[0] + red[1] + red[2] + red[3];
    int t = blockIdx.x * 256 + tid;   // grid.x = 4
    float acc = 0.f;
    const __hip_bfloat16* p = partials + (size_t)b * kJW * kT + t;
    #pragma unroll 4
    for (int w = 0; w < kJW; ++w) acc += __bfloat162float(p[(size_t)w * kT]);
    float m = acc / dsum;
    float hscale = 10.f / (1.f + expf(-hsr[0]));
    float mscale = 10.f / (1.f + expf(-msr[0]));
    float moff   = -10.f + 20.f / (1.f + expf(-mor[0]));
    float h = dec[b * kT + t];
    out[OFF_M + b * kT + t]    = m;
    out[OFF_BOUT + b * kT + t] = fmaf(hscale, h, fmaf(mscale, m, moff));
}

extern "C" void kernel_launch(void* const* d_in, const int* in_sizes, int n_in,
                              void* d_out, int out_size, void* d_ws, size_t ws_size,
                              hipStream_t stream) {
    (void)in_sizes; (void)n_in; (void)out_size; (void)ws_size;
    const float* enc_in = (const float*)d_in[0];
    const float* dec    = (const float*)d_in[1];
    const float* mask   = (const float*)d_in[2];
    const float* mesh   = (const float*)d_in[3];
    const float* Win    = (const float*)d_in[4];
    const float* bin    = (const float*)d_in[5];
    const float* Wr     = (const float*)d_in[6];
    const float* br     = (const float*)d_in[7];
    const float* Wout   = (const float*)d_in[8];
    const float* bout   = (const float*)d_in[9];
    const float* Ws     = (const float*)d_in[10];
    const float* bs     = (const float*)d_in[11];
    const float* Wm     = (const float*)d_in[12];
    const float* Wc     = (const float*)d_in[13];
    const float* bm     = (const float*)d_in[14];
    const float* Wo     = (const float*)d_in[15];
    const float* bo     = (const float*)d_in[16];
    const float* hsr    = (const float*)d_in[17];
    const float* msr    = (const float*)d_in[18];
    const float* mor    = (const float*)d_in[19];
    float* out = (float*)d_out;

    float* ws = (float*)d_ws;
    __hip_bfloat16* TAB      = (__hip_bfloat16*)(ws + WS_TAB);
    float* x1    = ws + WS_X1;
    float* x2    = ws + WS_X2;
    float* isf   = ws + WS_ISF;
    __hip_bfloat16* partials = (__hip_bfloat16*)(ws + WS_PART);
    float* densv = ws + WS_DENS;
    float* densp = ws + WS_DENSP;

    k_tab         <<<dim3(4, 101, kB),  256, 0, stream>>>(dec, TAB, densp);
    k_res_first   <<<dim3(161, 4),      256, 0, stream>>>(mesh, Win, bin, Wr, br, x1);
    k_res_t<false><<<dim3(161, 4),      256, 0, stream>>>(x1, Wr + 65536,  br + 256, x2, nullptr, nullptr);
    k_res_t<true> <<<dim3(161, 4),      256, 0, stream>>>(x2, Wr + 131072, br + 512, nullptr, Wout, densp);
    k_init        <<<dim3(21, kB),      256, 0, stream>>>(enc_in, mask, Ws, bs, Wc, mesh, densp,
                                                          bout, Wm, bm, Wo, bo, densv, isf, out);
    k_scan        <<<dim3(kJW, kB),      64, 0, stream>>>(mesh, densv, isf, TAB, partials, out);
    k_final       <<<dim3(4, kB),       256, 0, stream>>>(partials, densv, dec, hsr, msr, mor, out);
}